// Round 6
// baseline (173.960 us; speedup 1.0000x reference)
//
#include <hip/hip_runtime.h>
#include <hip/hip_bf16.h>
#include <math.h>

#define BATCH 2
#define SEQ 196
#define DMODEL 768
#define NHEAD 12
#define DHEAD 64
#define DFF 3072
#define NROWS (BATCH*SEQ)        // 392
#define NHROWS (NROWS*NHEAD)     // 4704

typedef __attribute__((ext_vector_type(8))) short short8;
typedef __attribute__((ext_vector_type(4))) float f32x4;

// bf16 scratch layout (element offsets within the bf16 pool)
#define XB_OFF   0
#define XB_LEN   (NROWS*DMODEL)            // 301056
#define WQ_OFF   (XB_OFF + XB_LEN)
#define WD_LEN   (DMODEL*DMODEL)           // 589824
#define WK_OFF   (WQ_OFF + WD_LEN)
#define WV_OFF   (WK_OFF + WD_LEN)
#define WO_OFF   (WV_OFF + WD_LEN)
#define W1_OFF   (WO_OFF + WD_LEN)
#define WF_LEN   (DFF*DMODEL)              // 2359296
#define W2_OFF   (W1_OFF + WF_LEN)
#define BF_TOTAL (W2_OFF + WF_LEN)         // 7378944 elems

// ---------- utilities ----------
__device__ __forceinline__ short f2bf(float f) {
  unsigned u = __builtin_bit_cast(unsigned, f);
  u += 0x7FFFu + ((u >> 16) & 1u);      // round-to-nearest-even
  return (short)(u >> 16);
}
__device__ __forceinline__ float bf2f(short s) {
  unsigned u = ((unsigned)(unsigned short)s) << 16;
  return __builtin_bit_cast(float, u);
}

__device__ __forceinline__ void block_reduce_sum4(float& a, float& b, float& c, float& d,
                                                  float* sbuf /*>=16 floats*/) {
  #pragma unroll
  for (int off = 32; off; off >>= 1) {
    a += __shfl_xor(a, off);
    b += __shfl_xor(b, off);
    c += __shfl_xor(c, off);
    d += __shfl_xor(d, off);
  }
  int wid = threadIdx.x >> 6;
  if ((threadIdx.x & 63) == 0) {
    sbuf[wid*4+0] = a; sbuf[wid*4+1] = b; sbuf[wid*4+2] = c; sbuf[wid*4+3] = d;
  }
  __syncthreads();
  a = sbuf[0] + sbuf[4] + sbuf[8]  + sbuf[12];
  b = sbuf[1] + sbuf[5] + sbuf[9]  + sbuf[13];
  c = sbuf[2] + sbuf[6] + sbuf[10] + sbuf[14];
  d = sbuf[3] + sbuf[7] + sbuf[11] + sbuf[15];
  __syncthreads();
}

// ---------- convert f32 -> bf16 pool (x + 6 weight matrices) ----------
__global__ __launch_bounds__(256) void cvt_bf16(
    const float* __restrict__ x,  const float* __restrict__ wq,
    const float* __restrict__ wk, const float* __restrict__ wv,
    const float* __restrict__ wo, const float* __restrict__ w1,
    const float* __restrict__ w2, short* __restrict__ d) {
  const float* s; size_t n, o;
  switch (blockIdx.y) {
    case 0: s = x;  n = XB_LEN; o = XB_OFF; break;
    case 1: s = wq; n = WD_LEN; o = WQ_OFF; break;
    case 2: s = wk; n = WD_LEN; o = WK_OFF; break;
    case 3: s = wv; n = WD_LEN; o = WV_OFF; break;
    case 4: s = wo; n = WD_LEN; o = WO_OFF; break;
    case 5: s = w1; n = WF_LEN; o = W1_OFF; break;
    default: s = w2; n = WF_LEN; o = W2_OFF; break;
  }
  size_t units = n >> 3;
  for (size_t u = (size_t)blockIdx.x*256 + threadIdx.x; u < units; u += (size_t)gridDim.x*256) {
    const f32x4* sp = (const f32x4*)(s + u*8);
    f32x4 v0 = sp[0], v1 = sp[1];
    short8 r;
    #pragma unroll
    for (int j = 0; j < 4; ++j) { r[j] = f2bf(v0[j]); r[j+4] = f2bf(v1[j]); }
    *(short8*)(d + o + u*8) = r;
  }
}

// ---------- bf16 MFMA GEMM: Y[n][m] = X[n][K] @ W[m][K]^T (bf16 in, f32 out) ----------
#define PITCH 72   // bf16 elems per LDS row (144B = 16B aligned; frag reads 2-way = free)
__global__ __launch_bounds__(256) void gemm_bf16(
    const short* __restrict__ X,
    const short* __restrict__ W1p, const short* __restrict__ W2p, const short* __restrict__ W3p,
    float* __restrict__ Y1, float* __restrict__ Y2, float* __restrict__ Y3,
    int n, int K, int m) {
  const short* W = W1p; float* Y = Y1;
  if (blockIdx.z == 1) { W = W2p; Y = Y2; }
  else if (blockIdx.z == 2) { W = W3p; Y = Y3; }

  __shared__ short As[64*PITCH];
  __shared__ short Bs[64*PITCH];
  const int tid  = threadIdx.x;
  const int lane = tid & 63;
  const int w    = tid >> 6, wr = w >> 1, wc = w & 1;
  const int brow = blockIdx.y * 64, bcol = blockIdx.x * 64;

  const int sr = tid >> 2, sc = (tid & 3) * 16;
  const bool rok = (brow + sr) < n;
  const short* xp = X + (size_t)(brow + sr) * K + sc;
  const short* wp = W + (size_t)(bcol + sr) * K + sc;

  f32x4 acc[2][2] = {};
  const int kgo = (lane >> 4) * 8;
  const short8 zero8 = {0,0,0,0,0,0,0,0};

  short8 xa0, xa1, wa0, wa1;
  if (rok) { xa0 = *(const short8*)(xp); xa1 = *(const short8*)(xp + 8); }
  else     { xa0 = zero8; xa1 = zero8; }
  wa0 = *(const short8*)(wp); wa1 = *(const short8*)(wp + 8);

  const int T = K / 64;
  for (int t = 0; t < T; ++t) {
    short8 xn0, xn1, wn0, wn1;
    const int kn = (t + 1 < T) ? (t + 1) * 64 : 0;
    if (rok) { xn0 = *(const short8*)(xp + kn); xn1 = *(const short8*)(xp + kn + 8); }
    else     { xn0 = zero8; xn1 = zero8; }
    wn0 = *(const short8*)(wp + kn); wn1 = *(const short8*)(wp + kn + 8);

    __syncthreads();
    *(short8*)&As[sr*PITCH + sc]     = xa0;
    *(short8*)&As[sr*PITCH + sc + 8] = xa1;
    *(short8*)&Bs[sr*PITCH + sc]     = wa0;
    *(short8*)&Bs[sr*PITCH + sc + 8] = wa1;
    __syncthreads();

    #pragma unroll
    for (int kk = 0; kk < 2; ++kk) {
      short8 a0 = *(const short8*)&As[(wr*32      + (lane & 15))*PITCH + kk*32 + kgo];
      short8 a1 = *(const short8*)&As[(wr*32 + 16 + (lane & 15))*PITCH + kk*32 + kgo];
      short8 b0 = *(const short8*)&Bs[(wc*32      + (lane & 15))*PITCH + kk*32 + kgo];
      short8 b1 = *(const short8*)&Bs[(wc*32 + 16 + (lane & 15))*PITCH + kk*32 + kgo];
      acc[0][0] = __builtin_amdgcn_mfma_f32_16x16x32_bf16(a0, b0, acc[0][0], 0, 0, 0);
      acc[0][1] = __builtin_amdgcn_mfma_f32_16x16x32_bf16(a0, b1, acc[0][1], 0, 0, 0);
      acc[1][0] = __builtin_amdgcn_mfma_f32_16x16x32_bf16(a1, b0, acc[1][0], 0, 0, 0);
      acc[1][1] = __builtin_amdgcn_mfma_f32_16x16x32_bf16(a1, b1, acc[1][1], 0, 0, 0);
    }
    xa0 = xn0; xa1 = xn1; wa0 = wn0; wa1 = wn1;
  }

  const int ccol = bcol + wc*32 + (lane & 15);
  #pragma unroll
  for (int mr = 0; mr < 2; ++mr) {
    #pragma unroll
    for (int j = 0; j < 4; ++j) {
      int grow = brow + wr*32 + mr*16 + (lane >> 4)*4 + j;
      if (grow < n) {
        float* yr = Y + (size_t)grow * m + ccol;
        yr[0]  = acc[mr][0][j];
        yr[16] = acc[mr][1][j];
      }
    }
  }
}

// ---------- hyp_linear post row ----------
__device__ __forceinline__ void hyp_post_row(const float* __restrict__ xr,
                                             const float* __restrict__ mr,
                                             const float* __restrict__ bias,
                                             float* __restrict__ orow,
                                             int din, int dout, float* sbuf) {
  float xs = 0.f, ms = 0.f, mb = 0.f, bb = 0.f;
  for (int i = threadIdx.x; i < din; i += 256) { float v = xr[i]; xs += v*v; }
  for (int i = threadIdx.x; i < dout; i += 256) {
    float v = mr[i], b = bias[i];
    ms += v*v; mb += v*b; bb += b*b;
  }
  block_reduce_sum4(xs, ms, mb, bb, sbuf);
  float xn  = sqrtf(fmaxf(xs, 1e-15f));
  float mxn = sqrtf(fmaxf(ms, 1e-15f));
  float art = atanhf(fminf(xn, 1.f - 1e-5f));
  float scm = tanhf(mxn/xn*art)/mxn;
  float x2 = scm*scm*ms;
  float y2 = bb;
  float xy = scm*mb;
  float den = fmaxf(1.f + 2.f*xy + x2*y2, 1e-15f);
  float ca = (1.f + 2.f*xy + y2) * scm / den;
  float cb = (1.f - x2) / den;
  for (int i = threadIdx.x; i < dout; i += 256)
    orow[i] = ca*mr[i] + cb*bias[i];
}

__global__ __launch_bounds__(256) void hyp_linear_post(const float* __restrict__ X,
                                                       const float* __restrict__ MX,
                                                       const float* __restrict__ bias,
                                                       float* __restrict__ out,
                                                       int din, int dout) {
  __shared__ float sbuf[16];
  int r = blockIdx.x;
  hyp_post_row(X + (size_t)r*din, MX + (size_t)r*dout, bias, out + (size_t)r*dout,
               din, dout, sbuf);
}

// fused QKV post: blockIdx.y = 0/1/2 -> q/k/v
__global__ __launch_bounds__(256) void qkv_post(const float* __restrict__ X,
                                                const float* __restrict__ MQ,
                                                const float* __restrict__ MK,
                                                const float* __restrict__ MV,
                                                const float* __restrict__ bq,
                                                const float* __restrict__ bk,
                                                const float* __restrict__ bv,
                                                float* __restrict__ oq,
                                                float* __restrict__ ok,
                                                float* __restrict__ ov) {
  __shared__ float sbuf[16];
  int r = blockIdx.x;
  const float* MX = MQ; const float* b = bq; float* o = oq;
  if (blockIdx.y == 1) { MX = MK; b = bk; o = ok; }
  else if (blockIdx.y == 2) { MX = MV; b = bv; o = ov; }
  hyp_post_row(X + (size_t)r*DMODEL, MX + (size_t)r*DMODEL, b, o + (size_t)r*DMODEL,
               DMODEL, DMODEL, sbuf);
}

// ---------- logmap0 per 64-elem head-row ----------
__global__ __launch_bounds__(256) void logmap0_rows64(const float* __restrict__ v,
                                                      float* __restrict__ lv, int nrows) {
  int row = blockIdx.x*4 + (threadIdx.x >> 6);
  if (row >= nrows) return;
  int lane = threadIdx.x & 63;
  float vv = v[(size_t)row*64 + lane];
  float s2 = vv*vv;
  #pragma unroll
  for (int off = 32; off; off >>= 1) s2 += __shfl_xor(s2, off);
  float n = sqrtf(fmaxf(s2, 1e-15f));
  float scl = atanhf(fminf(n, 1.f - 1e-5f))/n;
  lv[(size_t)row*64 + lane] = scl*vv;
}

// ---------- query-tiled fused attention: one block per (b,h, 14-query tile) ----------
// K staged TRANSPOSED bf16 [64][208]; lv bf16 [196][72]; Q-tile f32. ~61KB LDS.
#define TILE_I 14
#define NTILE  (SEQ/TILE_I)     // 14
#define KT_P 208
#define LV_P 72
__global__ __launch_bounds__(256) void attn_tiled(const float* __restrict__ q,
                                                  const float* __restrict__ k,
                                                  const float* __restrict__ lv,
                                                  const float* __restrict__ hs,
                                                  float* __restrict__ ao,
                                                  short* __restrict__ aob) {
  __shared__ short Kt[DHEAD*KT_P];      // [d][j] bf16, transposed
  __shared__ short LVs[SEQ*LV_P];       // [j][d] bf16
  __shared__ float Qs[TILE_I][DHEAD];
  __shared__ float q2s[TILE_I];
  __shared__ float k2s[SEQ];
  __shared__ float ps[SEQ];
  __shared__ float red[4];
  __shared__ float pvs[4][DHEAD];
  __shared__ float pssum[4];

  const int tile = blockIdx.x % NTILE, bh = blockIdx.x / NTILE;
  const int h = bh % NHEAD, b = bh / NHEAD;
  const int i0 = tile * TILE_I;
  const int tid = threadIdx.x;
  const int wid = tid >> 6, lane = tid & 63;
  const float maxn = 1.0f - 1e-5f;

  // stage K (transposed, clamped) : 196 rows x 4 segs of 16
  for (int u = tid; u < SEQ*4; u += 256) {
    int j = u >> 2, seg = (u & 3) << 4;
    const float* kr = k + ((size_t)(b*SEQ + j)*DMODEL) + h*DHEAD + seg;
    #pragma unroll
    for (int t = 0; t < 16; ++t)
      Kt[(seg + t)*KT_P + j] = f2bf(fminf(kr[t], maxn));
  }
  // stage LV (row-major)
  for (int u = tid; u < SEQ*4; u += 256) {
    int j = u >> 2, seg = (u & 3) << 4;
    const float* vr = lv + ((size_t)(b*SEQ + j)*DMODEL) + h*DHEAD + seg;
    #pragma unroll
    for (int t = 0; t < 16; ++t)
      LVs[j*LV_P + seg + t] = f2bf(vr[t]);
  }
  // stage Q tile (clamped)
  for (int u = tid; u < TILE_I*4; u += 256) {
    int qi = u >> 2, seg = (u & 3) << 4;
    const float* qr = q + ((size_t)(b*SEQ + i0 + qi)*DMODEL) + h*DHEAD + seg;
    #pragma unroll
    for (int t = 0; t < 16; ++t)
      Qs[qi][seg + t] = fminf(qr[t], maxn);
  }
  __syncthreads();
  // row norms
  if (tid < SEQ) {
    float s = 0.f;
    #pragma unroll
    for (int d = 0; d < DHEAD; ++d) { float kv = bf2f(Kt[d*KT_P + tid]); s += kv*kv; }
    k2s[tid] = s;
  }
  if (tid < TILE_I) {
    float s = 0.f;
    #pragma unroll
    for (int d = 0; d < DHEAD; ++d) { float qv = Qs[tid][d]; s += qv*qv; }
    q2s[tid] = s;
  }
  __syncthreads();

  const float hsv = hs[h] * 8.0f;

  for (int qi = 0; qi < TILE_I; ++qi) {
    float sval = -1e30f;
    if (tid < SEQ) {
      const float q2 = q2s[qi];
      float kq = 0.f;
      #pragma unroll
      for (int d = 0; d < DHEAD; ++d)
        kq += Qs[qi][d] * bf2f(Kt[d*KT_P + tid]);
      const float k2 = k2s[tid];
      float xy = -kq;
      float al = 1.f + 2.f*xy + q2;
      float be = 1.f - k2;
      float num2 = al*al*k2 + 2.f*al*be*xy + be*be*q2;
      float den  = fmaxf(1.f + 2.f*xy + k2*q2, 1e-15f);
      float dns  = num2/(den*den);
      float denom = (1.f - q2)*(1.f - k2) + 1e-15f;
      float arg = 1.f + 2.f*dns/denom;
      arg = fmaxf(arg, 1.f + 1e-7f);
      float dist = logf(arg + sqrtf(arg*arg - 1.f));
      sval = -dist / hsv;
    }
    // block max
    float mm = sval;
    #pragma unroll
    for (int off = 32; off; off >>= 1) mm = fmaxf(mm, __shfl_xor(mm, off));
    if (lane == 0) red[wid] = mm;
    __syncthreads();
    float m = fmaxf(fmaxf(red[0], red[1]), fmaxf(red[2], red[3]));
    float e = (tid < SEQ) ? expf(sval - m) : 0.f;
    if (tid < SEQ) ps[tid] = e;
    __syncthreads();
    // PV over this wave's j-range; fold denominator sum into the pass
    float acc = 0.f, psum = 0.f;
    const int j0 = wid * 49;
    #pragma unroll 7
    for (int jj = j0; jj < j0 + 49; ++jj) {
      float p = ps[jj];
      psum += p;
      acc += p * bf2f(LVs[jj*LV_P + lane]);
    }
    pvs[wid][lane] = acc;
    if (lane == 0) pssum[wid] = psum;
    __syncthreads();
    if (wid == 0) {
      float val = pvs[0][lane] + pvs[1][lane] + pvs[2][lane] + pvs[3][lane];
      float tot = pssum[0] + pssum[1] + pssum[2] + pssum[3];
      val /= tot;
      float s2 = val*val;
      #pragma unroll
      for (int off = 32; off; off >>= 1) s2 += __shfl_xor(s2, off);
      float n = sqrtf(fmaxf(s2, 1e-15f));
      float scl = tanhf(n)/n;
      float o = scl*val;
      size_t oidx = (size_t)(b*SEQ + i0 + qi)*DMODEL + h*DHEAD + lane;
      ao[oidx] = o;
      aob[oidx] = f2bf(o);
    }
    __syncthreads();
  }
}

// ---------- residual + hyp layer norm (optional bf16 copy) ----------
__global__ __launch_bounds__(256) void resid_ln(const float* __restrict__ X,
                                                const float* __restrict__ Y,
                                                const float* __restrict__ betap,
                                                const float* __restrict__ lnw,
                                                const float* __restrict__ lnb,
                                                float* __restrict__ out,
                                                short* __restrict__ outb) {
  __shared__ float sbuf[16];
  int r = blockIdx.x;
  const float* xr = X + (size_t)r*DMODEL;
  const float* yr = Y + (size_t)r*DMODEL;
  float xv[3], yv[3];
  float x2 = 0.f, yy = 0.f, xy = 0.f, dm = 0.f;
  #pragma unroll
  for (int l = 0; l < 3; ++l) {
    int i = threadIdx.x + l*256;
    xv[l] = xr[i]; yv[l] = yr[i];
    x2 += xv[l]*xv[l]; yy += yv[l]*yv[l]; xy += xv[l]*yv[l];
  }
  block_reduce_sum4(x2, yy, xy, dm, sbuf);
  float beta = betap[0];
  float ny = sqrtf(fmaxf(yy, 1e-15f));
  float scs = tanhf(beta * atanhf(fminf(ny, 1.f - 1e-5f))) / ny;
  float y2  = scs*scs*yy;
  float xys = scs*xy;
  float den = fmaxf(1.f + 2.f*xys + x2*y2, 1e-15f);
  float ca = (1.f + 2.f*xys + y2)/den;
  float cb = (1.f - x2)*scs/den;
  float hv[3]; float h2 = 0.f;
  #pragma unroll
  for (int l = 0; l < 3; ++l) { hv[l] = ca*xv[l] + cb*yv[l]; h2 += hv[l]*hv[l]; }
  float z1 = 0.f, z2 = 0.f, z3 = 0.f;
  block_reduce_sum4(h2, z1, z2, z3, sbuf);
  float nh = sqrtf(fmaxf(h2, 1e-15f));
  float scl = atanhf(fminf(nh, 1.f - 1e-5f))/nh;
  float tv[3]; float tsum = 0.f, tsq = 0.f;
  #pragma unroll
  for (int l = 0; l < 3; ++l) { tv[l] = scl*hv[l]; tsum += tv[l]; tsq += tv[l]*tv[l]; }
  float zz = 0.f, zw = 0.f;
  block_reduce_sum4(tsum, tsq, zz, zw, sbuf);
  float mu  = tsum * (1.f/768.f);
  float var = tsq * (1.f/768.f) - mu*mu;
  float rstd = rsqrtf(var + 1e-5f);
  float lnv[3]; float l2 = 0.f;
  #pragma unroll
  for (int l = 0; l < 3; ++l) {
    int i = threadIdx.x + l*256;
    lnv[l] = (tv[l] - mu)*rstd*lnw[i] + lnb[i];
    l2 += lnv[l]*lnv[l];
  }
  float w1 = 0.f, w2 = 0.f, w3 = 0.f;
  block_reduce_sum4(l2, w1, w2, w3, sbuf);
  float nl = sqrtf(fmaxf(l2, 1e-15f));
  float sce = tanhf(nl)/nl;
  #pragma unroll
  for (int l = 0; l < 3; ++l) {
    int i = threadIdx.x + l*256;
    float o = sce*lnv[l];
    out[(size_t)r*DMODEL + i] = o;
    if (outb) outb[(size_t)r*DMODEL + i] = f2bf(o);
  }
}

// ---------- mobius relu on FF rows (in place) + bf16 copy ----------
__global__ __launch_bounds__(256) void mobius_relu(float* __restrict__ f,
                                                   short* __restrict__ fb) {
  __shared__ float sbuf[16];
  int r = blockIdx.x;
  float* fr = f + (size_t)r*DFF;
  short* fbr = fb + (size_t)r*DFF;
  float fv[12];
  float s2 = 0.f, z1 = 0.f, z2 = 0.f, z3 = 0.f;
  #pragma unroll
  for (int l = 0; l < 12; ++l) { fv[l] = fr[threadIdx.x + l*256]; s2 += fv[l]*fv[l]; }
  block_reduce_sum4(s2, z1, z2, z3, sbuf);
  float n = sqrtf(fmaxf(s2, 1e-15f));
  float scl = atanhf(fminf(n, 1.f - 1e-5f))/n;
  float rv[12]; float r2 = 0.f;
  #pragma unroll
  for (int l = 0; l < 12; ++l) { rv[l] = fmaxf(scl*fv[l], 0.f); r2 += rv[l]*rv[l]; }
  float w1 = 0.f, w2 = 0.f, w3 = 0.f;
  block_reduce_sum4(r2, w1, w2, w3, sbuf);
  float nr = sqrtf(fmaxf(r2, 1e-15f));
  float sce = tanhf(nr)/nr;
  #pragma unroll
  for (int l = 0; l < 12; ++l) {
    float o = sce*rv[l];
    fr[threadIdx.x + l*256] = o;
    fbr[threadIdx.x + l*256] = f2bf(o);
  }
}

extern "C" void kernel_launch(void* const* d_in, const int* in_sizes, int n_in,
                              void* d_out, int out_size, void* d_ws, size_t ws_size,
                              hipStream_t stream) {
  const float* x    = (const float*)d_in[0];
  const float* wq   = (const float*)d_in[1];
  const float* bq   = (const float*)d_in[2];
  const float* wk   = (const float*)d_in[3];
  const float* bk   = (const float*)d_in[4];
  const float* wv   = (const float*)d_in[5];
  const float* bv   = (const float*)d_in[6];
  const float* wo   = (const float*)d_in[7];
  const float* bo   = (const float*)d_in[8];
  const float* hs   = (const float*)d_in[9];
  const float* w1   = (const float*)d_in[10];
  const float* b1   = (const float*)d_in[11];
  const float* w2   = (const float*)d_in[12];
  const float* b2   = (const float*)d_in[13];
  const float* beta = (const float*)d_in[14];
  const float* ln1w = (const float*)d_in[15];
  const float* ln1b = (const float*)d_in[16];
  const float* ln2w = (const float*)d_in[17];
  const float* ln2b = (const float*)d_in[18];
  float* out = (float*)d_out;

  char* base = (char*)d_ws;
  size_t off = 0;
  auto allocB = [&](size_t bytes) {
    off = (off + 63) & ~(size_t)63;
    void* p = base + off; off += bytes; return p;
  };
  short* bfp  = (short*)allocB((size_t)BF_TOTAL * 2);          // bf16 pool: xb + weights
  short* aob  = (short*)allocB((size_t)NROWS*DMODEL * 2);
  short* hbb  = (short*)allocB((size_t)NROWS*DMODEL * 2);
  short* fbb  = (short*)allocB((size_t)NROWS*DFF * 2);
  float* tq   = (float*)allocB((size_t)NROWS*DMODEL * 4);
  float* tk   = (float*)allocB((size_t)NROWS*DMODEL * 4);      // later: aop
  float* tv   = (float*)allocB((size_t)NROWS*DMODEL * 4);      // later: f2
  float* qb   = (float*)allocB((size_t)NROWS*DMODEL * 4);
  float* kb   = (float*)allocB((size_t)NROWS*DMODEL * 4);
  float* vb   = (float*)allocB((size_t)NROWS*DMODEL * 4);
  float* lv   = (float*)allocB((size_t)NROWS*DMODEL * 4);
  float* ao   = (float*)allocB((size_t)NROWS*DMODEL * 4);
  float* hb   = (float*)allocB((size_t)NROWS*DMODEL * 4);
  float* tmpF = (float*)allocB((size_t)NROWS*DFF * 4);
  float* fbuf = (float*)allocB((size_t)NROWS*DFF * 4);

  const short* xb  = bfp + XB_OFF;
  const short* wqb = bfp + WQ_OFF;
  const short* wkb = bfp + WK_OFF;
  const short* wvb = bfp + WV_OFF;
  const short* wob = bfp + WO_OFF;
  const short* w1b = bfp + W1_OFF;
  const short* w2b = bfp + W2_OFF;

  dim3 blk(256);
  dim3 gCVT(1152, 7);
  dim3 gQKV(DMODEL/64, (NROWS+63)/64, 3);   // 12 x 7 x 3
  dim3 gD(DMODEL/64,  (NROWS+63)/64, 1);    // 12 x 7
  dim3 gF(DFF/64,     (NROWS+63)/64, 1);    // 48 x 7

  // convert x + all weights to bf16
  cvt_bf16<<<gCVT, blk, 0, stream>>>(x, wq, wk, wv, wo, w1, w2, bfp);

  // QKV projections
  gemm_bf16<<<gQKV, blk, 0, stream>>>(xb, wqb, wkb, wvb, tq, tk, tv, NROWS, DMODEL, DMODEL);
  qkv_post<<<dim3(NROWS,3), blk, 0, stream>>>(x, tq, tk, tv, bq, bk, bv, qb, kb, vb);

  // attention
  logmap0_rows64<<<(NHROWS+3)/4, blk, 0, stream>>>(vb, lv, NHROWS);
  attn_tiled<<<BATCH*NHEAD*NTILE, blk, 0, stream>>>(qb, kb, lv, hs, ao, aob);

  // output projection
  gemm_bf16<<<gD, blk, 0, stream>>>(aob, wob, wob, wob, tq, tq, tq, NROWS, DMODEL, DMODEL);
  hyp_linear_post<<<NROWS, blk, 0, stream>>>(ao, tq, bo, tk, DMODEL, DMODEL);

  // residual 1 + hyp layer norm
  resid_ln<<<NROWS, blk, 0, stream>>>(x, tk, beta, ln1w, ln1b, hb, hbb);

  // FFN
  gemm_bf16<<<gF, blk, 0, stream>>>(hbb, w1b, w1b, w1b, tmpF, tmpF, tmpF, NROWS, DMODEL, DFF);
  hyp_linear_post<<<NROWS, blk, 0, stream>>>(hb, tmpF, b1, fbuf, DMODEL, DFF);
  mobius_relu<<<NROWS, blk, 0, stream>>>(fbuf, fbb);
  gemm_bf16<<<gD, blk, 0, stream>>>(fbb, w2b, w2b, w2b, tq, tq, tq, NROWS, DFF, DMODEL);
  hyp_linear_post<<<NROWS, blk, 0, stream>>>(fbuf, tq, b2, tv, DFF, DMODEL);

  // residual 2 + hyp layer norm -> out
  resid_ln<<<NROWS, blk, 0, stream>>>(hb, tv, beta, ln2w, ln2b, out, nullptr);
}

// Round 7
// 140.003 us; speedup vs baseline: 1.2425x; 1.2425x over previous
//
#include <hip/hip_runtime.h>
#include <hip/hip_bf16.h>
#include <math.h>

#define BATCH 2
#define SEQ 196
#define DMODEL 768
#define NHEAD 12
#define DHEAD 64
#define DFF 3072
#define NROWS (BATCH*SEQ)        // 392
#define NBH   (BATCH*NHEAD)     // 24
#define NHROWS (NBH*SEQ)        // 4704

typedef __attribute__((ext_vector_type(8))) short short8;
typedef __attribute__((ext_vector_type(4))) float f32x4;

// bf16 scratch layout (element offsets within the bf16 pool)
#define XB_OFF   0
#define XB_LEN   (NROWS*DMODEL)            // 301056
#define WQ_OFF   (XB_OFF + XB_LEN)
#define WD_LEN   (DMODEL*DMODEL)           // 589824
#define WK_OFF   (WQ_OFF + WD_LEN)
#define WV_OFF   (WK_OFF + WD_LEN)
#define WO_OFF   (WV_OFF + WD_LEN)
#define W1_OFF   (WO_OFF + WD_LEN)
#define WF_LEN   (DFF*DMODEL)              // 2359296
#define W2_OFF   (W1_OFF + WF_LEN)
#define BF_TOTAL (W2_OFF + WF_LEN)         // 7378944 elems

// ---------- utilities ----------
__device__ __forceinline__ short f2bf(float f) {
  unsigned u = __builtin_bit_cast(unsigned, f);
  u += 0x7FFFu + ((u >> 16) & 1u);      // round-to-nearest-even
  return (short)(u >> 16);
}
__device__ __forceinline__ float bf2f(short s) {
  unsigned u = ((unsigned)(unsigned short)s) << 16;
  return __builtin_bit_cast(float, u);
}
__device__ __forceinline__ float wave_sum64(float v) {
  #pragma unroll
  for (int off = 32; off; off >>= 1) v += __shfl_xor(v, off);
  return v;
}
__device__ __forceinline__ float wave_max64(float v) {
  #pragma unroll
  for (int off = 32; off; off >>= 1) v = fmaxf(v, __shfl_xor(v, off));
  return v;
}

__device__ __forceinline__ void block_reduce_sum4(float& a, float& b, float& c, float& d,
                                                  float* sbuf /*>=16 floats*/) {
  #pragma unroll
  for (int off = 32; off; off >>= 1) {
    a += __shfl_xor(a, off);
    b += __shfl_xor(b, off);
    c += __shfl_xor(c, off);
    d += __shfl_xor(d, off);
  }
  int wid = threadIdx.x >> 6;
  if ((threadIdx.x & 63) == 0) {
    sbuf[wid*4+0] = a; sbuf[wid*4+1] = b; sbuf[wid*4+2] = c; sbuf[wid*4+3] = d;
  }
  __syncthreads();
  a = sbuf[0] + sbuf[4] + sbuf[8]  + sbuf[12];
  b = sbuf[1] + sbuf[5] + sbuf[9]  + sbuf[13];
  c = sbuf[2] + sbuf[6] + sbuf[10] + sbuf[14];
  d = sbuf[3] + sbuf[7] + sbuf[11] + sbuf[15];
  __syncthreads();
}

// ---------- convert f32 -> bf16 pool (x + 6 weight matrices) ----------
__global__ __launch_bounds__(256) void cvt_bf16(
    const float* __restrict__ x,  const float* __restrict__ wq,
    const float* __restrict__ wk, const float* __restrict__ wv,
    const float* __restrict__ wo, const float* __restrict__ w1,
    const float* __restrict__ w2, short* __restrict__ d) {
  const float* s; size_t n, o;
  switch (blockIdx.y) {
    case 0: s = x;  n = XB_LEN; o = XB_OFF; break;
    case 1: s = wq; n = WD_LEN; o = WQ_OFF; break;
    case 2: s = wk; n = WD_LEN; o = WK_OFF; break;
    case 3: s = wv; n = WD_LEN; o = WV_OFF; break;
    case 4: s = wo; n = WD_LEN; o = WO_OFF; break;
    case 5: s = w1; n = WF_LEN; o = W1_OFF; break;
    default: s = w2; n = WF_LEN; o = W2_OFF; break;
  }
  size_t units = n >> 3;
  for (size_t u = (size_t)blockIdx.x*256 + threadIdx.x; u < units; u += (size_t)gridDim.x*256) {
    const f32x4* sp = (const f32x4*)(s + u*8);
    f32x4 v0 = sp[0], v1 = sp[1];
    short8 r;
    #pragma unroll
    for (int j = 0; j < 4; ++j) { r[j] = f2bf(v0[j]); r[j+4] = f2bf(v1[j]); }
    *(short8*)(d + o + u*8) = r;
  }
}

// ---------- bf16 MFMA GEMM: Y[n][m] = X[n][K] @ W[m][K]^T (bf16 in, f32 out) ----------
#define PITCH 72   // bf16 elems per LDS row (144B = 16B aligned)
__global__ __launch_bounds__(256) void gemm_bf16(
    const short* __restrict__ X,
    const short* __restrict__ W1p, const short* __restrict__ W2p, const short* __restrict__ W3p,
    float* __restrict__ Y1, float* __restrict__ Y2, float* __restrict__ Y3,
    int n, int K, int m) {
  const short* W = W1p; float* Y = Y1;
  if (blockIdx.z == 1) { W = W2p; Y = Y2; }
  else if (blockIdx.z == 2) { W = W3p; Y = Y3; }

  __shared__ short As[64*PITCH];
  __shared__ short Bs[64*PITCH];
  const int tid  = threadIdx.x;
  const int lane = tid & 63;
  const int w    = tid >> 6, wr = w >> 1, wc = w & 1;
  const int brow = blockIdx.y * 64, bcol = blockIdx.x * 64;

  const int sr = tid >> 2, sc = (tid & 3) * 16;
  const bool rok = (brow + sr) < n;
  const short* xp = X + (size_t)(brow + sr) * K + sc;
  const short* wp = W + (size_t)(bcol + sr) * K + sc;

  f32x4 acc[2][2] = {};
  const int kgo = (lane >> 4) * 8;
  const short8 zero8 = {0,0,0,0,0,0,0,0};

  short8 xa0, xa1, wa0, wa1;
  if (rok) { xa0 = *(const short8*)(xp); xa1 = *(const short8*)(xp + 8); }
  else     { xa0 = zero8; xa1 = zero8; }
  wa0 = *(const short8*)(wp); wa1 = *(const short8*)(wp + 8);

  const int T = K / 64;
  for (int t = 0; t < T; ++t) {
    short8 xn0, xn1, wn0, wn1;
    const int kn = (t + 1 < T) ? (t + 1) * 64 : 0;
    if (rok) { xn0 = *(const short8*)(xp + kn); xn1 = *(const short8*)(xp + kn + 8); }
    else     { xn0 = zero8; xn1 = zero8; }
    wn0 = *(const short8*)(wp + kn); wn1 = *(const short8*)(wp + kn + 8);

    __syncthreads();
    *(short8*)&As[sr*PITCH + sc]     = xa0;
    *(short8*)&As[sr*PITCH + sc + 8] = xa1;
    *(short8*)&Bs[sr*PITCH + sc]     = wa0;
    *(short8*)&Bs[sr*PITCH + sc + 8] = wa1;
    __syncthreads();

    #pragma unroll
    for (int kk = 0; kk < 2; ++kk) {
      short8 a0 = *(const short8*)&As[(wr*32      + (lane & 15))*PITCH + kk*32 + kgo];
      short8 a1 = *(const short8*)&As[(wr*32 + 16 + (lane & 15))*PITCH + kk*32 + kgo];
      short8 b0 = *(const short8*)&Bs[(wc*32      + (lane & 15))*PITCH + kk*32 + kgo];
      short8 b1 = *(const short8*)&Bs[(wc*32 + 16 + (lane & 15))*PITCH + kk*32 + kgo];
      acc[0][0] = __builtin_amdgcn_mfma_f32_16x16x32_bf16(a0, b0, acc[0][0], 0, 0, 0);
      acc[0][1] = __builtin_amdgcn_mfma_f32_16x16x32_bf16(a0, b1, acc[0][1], 0, 0, 0);
      acc[1][0] = __builtin_amdgcn_mfma_f32_16x16x32_bf16(a1, b0, acc[1][0], 0, 0, 0);
      acc[1][1] = __builtin_amdgcn_mfma_f32_16x16x32_bf16(a1, b1, acc[1][1], 0, 0, 0);
    }
    xa0 = xn0; xa1 = xn1; wa0 = wn0; wa1 = wn1;
  }

  const int ccol = bcol + wc*32 + (lane & 15);
  #pragma unroll
  for (int mr = 0; mr < 2; ++mr) {
    #pragma unroll
    for (int j = 0; j < 4; ++j) {
      int grow = brow + wr*32 + mr*16 + (lane >> 4)*4 + j;
      if (grow < n) {
        float* yr = Y + (size_t)grow * m + ccol;
        yr[0]  = acc[mr][0][j];
        yr[16] = acc[mr][1][j];
      }
    }
  }
}

// ---------- batched S = Q @ K^T per (b,h): 196x196, K-dim 64 ----------
#define S_P 208
__global__ __launch_bounds__(256) void gemm_qk(const short* __restrict__ Q,
                                               const short* __restrict__ Kh,
                                               float* __restrict__ Sall) {
  const int bh = blockIdx.z;
  const short* Xp = Q  + (size_t)bh*SEQ*DHEAD;
  const short* Wp = Kh + (size_t)bh*SEQ*DHEAD;
  float* Y = Sall + (size_t)bh*SEQ*S_P;

  __shared__ short As[64*PITCH];
  __shared__ short Bs[64*PITCH];
  const int tid = threadIdx.x, lane = tid & 63;
  const int w = tid >> 6, wr = w >> 1, wc = w & 1;
  const int brow = blockIdx.y*64, bcol = blockIdx.x*64;
  const int sr = tid >> 2, sc = (tid & 3)*16;
  const short8 zero8 = {0,0,0,0,0,0,0,0};

  short8 xa0, xa1, wa0, wa1;
  if (brow + sr < SEQ) { const short* p = Xp + (size_t)(brow+sr)*DHEAD + sc; xa0 = *(const short8*)p; xa1 = *(const short8*)(p+8); }
  else { xa0 = zero8; xa1 = zero8; }
  if (bcol + sr < SEQ) { const short* p = Wp + (size_t)(bcol+sr)*DHEAD + sc; wa0 = *(const short8*)p; wa1 = *(const short8*)(p+8); }
  else { wa0 = zero8; wa1 = zero8; }

  *(short8*)&As[sr*PITCH + sc]     = xa0;
  *(short8*)&As[sr*PITCH + sc + 8] = xa1;
  *(short8*)&Bs[sr*PITCH + sc]     = wa0;
  *(short8*)&Bs[sr*PITCH + sc + 8] = wa1;
  __syncthreads();

  f32x4 acc[2][2] = {};
  const int kgo = (lane >> 4)*8;
  #pragma unroll
  for (int kk = 0; kk < 2; ++kk) {
    short8 a0 = *(const short8*)&As[(wr*32      + (lane & 15))*PITCH + kk*32 + kgo];
    short8 a1 = *(const short8*)&As[(wr*32 + 16 + (lane & 15))*PITCH + kk*32 + kgo];
    short8 b0 = *(const short8*)&Bs[(wc*32      + (lane & 15))*PITCH + kk*32 + kgo];
    short8 b1 = *(const short8*)&Bs[(wc*32 + 16 + (lane & 15))*PITCH + kk*32 + kgo];
    acc[0][0] = __builtin_amdgcn_mfma_f32_16x16x32_bf16(a0, b0, acc[0][0], 0, 0, 0);
    acc[0][1] = __builtin_amdgcn_mfma_f32_16x16x32_bf16(a0, b1, acc[0][1], 0, 0, 0);
    acc[1][0] = __builtin_amdgcn_mfma_f32_16x16x32_bf16(a1, b0, acc[1][0], 0, 0, 0);
    acc[1][1] = __builtin_amdgcn_mfma_f32_16x16x32_bf16(a1, b1, acc[1][1], 0, 0, 0);
  }

  const int ccol = bcol + wc*32 + (lane & 15);
  #pragma unroll
  for (int mr = 0; mr < 2; ++mr) {
    #pragma unroll
    for (int j = 0; j < 4; ++j) {
      int grow = brow + wr*32 + mr*16 + (lane >> 4)*4 + j;
      if (grow < SEQ) {
        float* yr = Y + (size_t)grow*S_P + ccol;
        if (ccol < SEQ)      yr[0]  = acc[mr][0][j];
        if (ccol + 16 < SEQ) yr[16] = acc[mr][1][j];
      }
    }
  }
}

// ---------- dist transform + softmax, one wave per score row ----------
#define P_P 256
__global__ __launch_bounds__(256) void soft_dist(const float* __restrict__ Sall,
                                                 const float* __restrict__ q2s,
                                                 const float* __restrict__ k2s,
                                                 const float* __restrict__ hs,
                                                 short* __restrict__ P) {
  const int row  = blockIdx.x*4 + (threadIdx.x >> 6);   // bh*SEQ + i
  const int lane = threadIdx.x & 63;
  const int bh = row / SEQ;
  const int h  = bh % NHEAD;
  const float q2 = q2s[row];
  const float inv_hsv = 1.f / (hs[h] * 8.0f);
  const float* srow = Sall + (size_t)row*S_P;

  float sv[4];
  #pragma unroll
  for (int c = 0; c < 4; ++c) {
    int j = c*64 + lane;
    if (j < SEQ) {
      float kq = srow[j];
      float k2 = k2s[(size_t)bh*SEQ + j];
      float xy = -kq;
      float al = 1.f + 2.f*xy + q2;
      float be = 1.f - k2;
      float num2 = al*al*k2 + 2.f*al*be*xy + be*be*q2;
      float den  = fmaxf(1.f + 2.f*xy + k2*q2, 1e-15f);
      float dns  = num2/(den*den);
      float denom = (1.f - q2)*(1.f - k2) + 1e-15f;
      float arg = fmaxf(1.f + 2.f*dns/denom, 1.f + 1e-7f);
      float dist = logf(arg + sqrtf(arg*arg - 1.f));
      sv[c] = -dist * inv_hsv;
    } else sv[c] = -1e30f;
  }
  float m = wave_max64(fmaxf(fmaxf(sv[0], sv[1]), fmaxf(sv[2], sv[3])));
  float e[4]; float sum = 0.f;
  #pragma unroll
  for (int c = 0; c < 4; ++c) {
    e[c] = (c*64 + lane < SEQ) ? expf(sv[c] - m) : 0.f;
    sum += e[c];
  }
  sum = wave_sum64(sum);
  float inv = 1.f / sum;
  short* prow = P + (size_t)row*P_P;
  #pragma unroll
  for (int c = 0; c < 4; ++c) prow[c*64 + lane] = f2bf(e[c]*inv);
}

// ---------- batched PV = P @ lvT^T per (b,h): 196x64, K-dim 256 ----------
__global__ __launch_bounds__(256) void gemm_pv(const short* __restrict__ P,
                                               const short* __restrict__ lvT,
                                               float* __restrict__ Yall) {
  const int bh = blockIdx.z;
  const short* Xp = P   + (size_t)bh*SEQ*P_P;     // 196 rows, stride 256
  const short* Wp = lvT + (size_t)bh*DHEAD*P_P;   // 64 rows, stride 256
  float* Y = Yall + (size_t)bh*SEQ*DHEAD;

  __shared__ short As[64*PITCH];
  __shared__ short Bs[64*PITCH];
  const int tid = threadIdx.x, lane = tid & 63;
  const int w = tid >> 6, wr = w >> 1, wc = w & 1;
  const int brow = blockIdx.y*64;
  const int sr = tid >> 2, sc = (tid & 3)*16;
  const bool rok = (brow + sr) < SEQ;
  const short* xp = Xp + (size_t)(brow + sr)*P_P + sc;
  const short* wp = Wp + (size_t)sr*P_P + sc;
  const short8 zero8 = {0,0,0,0,0,0,0,0};

  f32x4 acc[2][2] = {};
  const int kgo = (lane >> 4)*8;

  short8 xa0, xa1, wa0, wa1;
  if (rok) { xa0 = *(const short8*)(xp); xa1 = *(const short8*)(xp + 8); }
  else     { xa0 = zero8; xa1 = zero8; }
  wa0 = *(const short8*)(wp); wa1 = *(const short8*)(wp + 8);

  #pragma unroll
  for (int t = 0; t < 4; ++t) {
    short8 xn0, xn1, wn0, wn1;
    const int kn = (t + 1 < 4) ? (t + 1)*64 : 0;
    if (rok) { xn0 = *(const short8*)(xp + kn); xn1 = *(const short8*)(xp + kn + 8); }
    else     { xn0 = zero8; xn1 = zero8; }
    wn0 = *(const short8*)(wp + kn); wn1 = *(const short8*)(wp + kn + 8);

    __syncthreads();
    *(short8*)&As[sr*PITCH + sc]     = xa0;
    *(short8*)&As[sr*PITCH + sc + 8] = xa1;
    *(short8*)&Bs[sr*PITCH + sc]     = wa0;
    *(short8*)&Bs[sr*PITCH + sc + 8] = wa1;
    __syncthreads();

    #pragma unroll
    for (int kk = 0; kk < 2; ++kk) {
      short8 a0 = *(const short8*)&As[(wr*32      + (lane & 15))*PITCH + kk*32 + kgo];
      short8 a1 = *(const short8*)&As[(wr*32 + 16 + (lane & 15))*PITCH + kk*32 + kgo];
      short8 b0 = *(const short8*)&Bs[(wc*32      + (lane & 15))*PITCH + kk*32 + kgo];
      short8 b1 = *(const short8*)&Bs[(wc*32 + 16 + (lane & 15))*PITCH + kk*32 + kgo];
      acc[0][0] = __builtin_amdgcn_mfma_f32_16x16x32_bf16(a0, b0, acc[0][0], 0, 0, 0);
      acc[0][1] = __builtin_amdgcn_mfma_f32_16x16x32_bf16(a0, b1, acc[0][1], 0, 0, 0);
      acc[1][0] = __builtin_amdgcn_mfma_f32_16x16x32_bf16(a1, b0, acc[1][0], 0, 0, 0);
      acc[1][1] = __builtin_amdgcn_mfma_f32_16x16x32_bf16(a1, b1, acc[1][1], 0, 0, 0);
    }
    xa0 = xn0; xa1 = xn1; wa0 = wn0; wa1 = wn1;
  }

  const int ccol = wc*32 + (lane & 15);   // m = 64, single x-tile
  #pragma unroll
  for (int mr = 0; mr < 2; ++mr) {
    #pragma unroll
    for (int j = 0; j < 4; ++j) {
      int grow = brow + wr*32 + mr*16 + (lane >> 4)*4 + j;
      if (grow < SEQ) {
        float* yr = Y + (size_t)grow*DHEAD + ccol;
        yr[0]  = acc[mr][0][j];
        yr[16] = acc[mr][1][j];
      }
    }
  }
}

// ---------- expmap0 per 64-wide head-row of raw PV -> ao (f32) + aob (bf16) ----------
__global__ __launch_bounds__(256) void expmap_rows(const float* __restrict__ pv,
                                                   float* __restrict__ ao,
                                                   short* __restrict__ aob) {
  const int row  = blockIdx.x*4 + (threadIdx.x >> 6);   // bh*SEQ + i
  const int lane = threadIdx.x & 63;
  float v = pv[(size_t)row*DHEAD + lane];
  float s2 = wave_sum64(v*v);
  float n = sqrtf(fmaxf(s2, 1e-15f));
  float o = tanhf(n)/n * v;
  int bh = row / SEQ, i = row % SEQ, b = bh / NHEAD, h = bh % NHEAD;
  size_t idx = ((size_t)(b*SEQ + i)*NHEAD + h)*64 + lane;
  ao[idx] = o;
  aob[idx] = f2bf(o);
}

// ---------- hyp_linear post row ----------
__device__ __forceinline__ void hyp_post_row(const float* __restrict__ xr,
                                             const float* __restrict__ mr,
                                             const float* __restrict__ bias,
                                             float* __restrict__ orow,
                                             int din, int dout, float* sbuf) {
  float xs = 0.f, ms = 0.f, mb = 0.f, bb = 0.f;
  for (int i = threadIdx.x; i < din; i += 256) { float v = xr[i]; xs += v*v; }
  for (int i = threadIdx.x; i < dout; i += 256) {
    float v = mr[i], b = bias[i];
    ms += v*v; mb += v*b; bb += b*b;
  }
  block_reduce_sum4(xs, ms, mb, bb, sbuf);
  float xn  = sqrtf(fmaxf(xs, 1e-15f));
  float mxn = sqrtf(fmaxf(ms, 1e-15f));
  float art = atanhf(fminf(xn, 1.f - 1e-5f));
  float scm = tanhf(mxn/xn*art)/mxn;
  float x2 = scm*scm*ms;
  float y2 = bb;
  float xy = scm*mb;
  float den = fmaxf(1.f + 2.f*xy + x2*y2, 1e-15f);
  float ca = (1.f + 2.f*xy + y2) * scm / den;
  float cb = (1.f - x2) / den;
  for (int i = threadIdx.x; i < dout; i += 256)
    orow[i] = ca*mr[i] + cb*bias[i];
}

__global__ __launch_bounds__(256) void hyp_linear_post(const float* __restrict__ X,
                                                       const float* __restrict__ MX,
                                                       const float* __restrict__ bias,
                                                       float* __restrict__ out,
                                                       int din, int dout) {
  __shared__ float sbuf[16];
  int r = blockIdx.x;
  hyp_post_row(X + (size_t)r*din, MX + (size_t)r*dout, bias, out + (size_t)r*dout,
               din, dout, sbuf);
}

// ---------- fused QKV post: hyp_linear epilogue + head-major clamped bf16 + norms + logmap0(v) ----------
__global__ __launch_bounds__(256) void qkv_post(const float* __restrict__ X,
                                                const float* __restrict__ MQ,
                                                const float* __restrict__ MK,
                                                const float* __restrict__ MV,
                                                const float* __restrict__ bq,
                                                const float* __restrict__ bk,
                                                const float* __restrict__ bv,
                                                short* __restrict__ qhb,
                                                short* __restrict__ khb,
                                                float* __restrict__ q2s,
                                                float* __restrict__ k2s,
                                                short* __restrict__ lvT) {
  __shared__ float sbuf[16];
  const int r = blockIdx.x;            // b*SEQ + s
  const int b = r / SEQ, s = r % SEQ;
  const int y = blockIdx.y;
  const float* MX   = (y == 0) ? MQ : (y == 1) ? MK : MV;
  const float* bias = (y == 0) ? bq : (y == 1) ? bk : bv;
  const float* xr = X + (size_t)r*DMODEL;
  const float* mr = MX + (size_t)r*DMODEL;
  const int tid = threadIdx.x, wid = tid >> 6, lane = tid & 63;
  const float maxn = 1.0f - 1e-5f;

  float xs = 0.f, ms = 0.f, mb = 0.f, bb = 0.f;
  float mv[3], bvv[3];
  #pragma unroll
  for (int l = 0; l < 3; ++l) {
    int i = tid + l*256;
    float xv = xr[i];
    mv[l] = mr[i]; bvv[l] = bias[i];
    xs += xv*xv; ms += mv[l]*mv[l]; mb += mv[l]*bvv[l]; bb += bvv[l]*bvv[l];
  }
  block_reduce_sum4(xs, ms, mb, bb, sbuf);
  float xn  = sqrtf(fmaxf(xs, 1e-15f));
  float mxn = sqrtf(fmaxf(ms, 1e-15f));
  float art = atanhf(fminf(xn, maxn));
  float scm = tanhf(mxn/xn*art)/mxn;
  float x2 = scm*scm*ms;
  float y2 = bb;
  float xy = scm*mb;
  float den = fmaxf(1.f + 2.f*xy + x2*y2, 1e-15f);
  float ca = (1.f + 2.f*xy + y2) * scm / den;
  float cb = (1.f - x2) / den;

  #pragma unroll
  for (int l = 0; l < 3; ++l) {
    float o = ca*mv[l] + cb*bvv[l];
    int h = l*4 + wid;
    size_t hr = (size_t)(b*NHEAD + h)*SEQ + s;
    if (y < 2) {
      short c16 = f2bf(fminf(o, maxn));
      float cf = bf2f(c16);
      float nn = wave_sum64(cf*cf);
      if (y == 0) {
        qhb[hr*64 + lane] = c16;
        if (lane == 0) q2s[hr] = nn;
      } else {
        khb[hr*64 + lane] = c16;
        if (lane == 0) k2s[hr] = nn;
      }
    } else {
      float nn = wave_sum64(o*o);
      float n = sqrtf(fmaxf(nn, 1e-15f));
      float scl = atanhf(fminf(n, maxn))/n;
      lvT[((size_t)(b*NHEAD + h)*DHEAD + lane)*P_P + s] = f2bf(scl*o);
    }
  }
}

// ---------- residual + hyp layer norm (optional bf16 copy) ----------
__global__ __launch_bounds__(256) void resid_ln(const float* __restrict__ X,
                                                const float* __restrict__ Y,
                                                const float* __restrict__ betap,
                                                const float* __restrict__ lnw,
                                                const float* __restrict__ lnb,
                                                float* __restrict__ out,
                                                short* __restrict__ outb) {
  __shared__ float sbuf[16];
  int r = blockIdx.x;
  const float* xr = X + (size_t)r*DMODEL;
  const float* yr = Y + (size_t)r*DMODEL;
  float xv[3], yv[3];
  float x2 = 0.f, yy = 0.f, xy = 0.f, dm = 0.f;
  #pragma unroll
  for (int l = 0; l < 3; ++l) {
    int i = threadIdx.x + l*256;
    xv[l] = xr[i]; yv[l] = yr[i];
    x2 += xv[l]*xv[l]; yy += yv[l]*yv[l]; xy += xv[l]*yv[l];
  }
  block_reduce_sum4(x2, yy, xy, dm, sbuf);
  float beta = betap[0];
  float ny = sqrtf(fmaxf(yy, 1e-15f));
  float scs = tanhf(beta * atanhf(fminf(ny, 1.f - 1e-5f))) / ny;
  float y2  = scs*scs*yy;
  float xys = scs*xy;
  float den = fmaxf(1.f + 2.f*xys + x2*y2, 1e-15f);
  float ca = (1.f + 2.f*xys + y2)/den;
  float cb = (1.f - x2)*scs/den;
  float hv[3]; float h2 = 0.f;
  #pragma unroll
  for (int l = 0; l < 3; ++l) { hv[l] = ca*xv[l] + cb*yv[l]; h2 += hv[l]*hv[l]; }
  float z1 = 0.f, z2 = 0.f, z3 = 0.f;
  block_reduce_sum4(h2, z1, z2, z3, sbuf);
  float nh = sqrtf(fmaxf(h2, 1e-15f));
  float scl = atanhf(fminf(nh, 1.f - 1e-5f))/nh;
  float tv[3]; float tsum = 0.f, tsq = 0.f;
  #pragma unroll
  for (int l = 0; l < 3; ++l) { tv[l] = scl*hv[l]; tsum += tv[l]; tsq += tv[l]*tv[l]; }
  float zz = 0.f, zw = 0.f;
  block_reduce_sum4(tsum, tsq, zz, zw, sbuf);
  float mu  = tsum * (1.f/768.f);
  float var = tsq * (1.f/768.f) - mu*mu;
  float rstd = rsqrtf(var + 1e-5f);
  float lnv[3]; float l2 = 0.f;
  #pragma unroll
  for (int l = 0; l < 3; ++l) {
    int i = threadIdx.x + l*256;
    lnv[l] = (tv[l] - mu)*rstd*lnw[i] + lnb[i];
    l2 += lnv[l]*lnv[l];
  }
  float w1 = 0.f, w2 = 0.f, w3 = 0.f;
  block_reduce_sum4(l2, w1, w2, w3, sbuf);
  float nl = sqrtf(fmaxf(l2, 1e-15f));
  float sce = tanhf(nl)/nl;
  #pragma unroll
  for (int l = 0; l < 3; ++l) {
    int i = threadIdx.x + l*256;
    float o = sce*lnv[l];
    out[(size_t)r*DMODEL + i] = o;
    if (outb) outb[(size_t)r*DMODEL + i] = f2bf(o);
  }
}

// ---------- mobius relu on FF rows (in place) + bf16 copy ----------
__global__ __launch_bounds__(256) void mobius_relu(float* __restrict__ f,
                                                   short* __restrict__ fb) {
  __shared__ float sbuf[16];
  int r = blockIdx.x;
  float* fr = f + (size_t)r*DFF;
  short* fbr = fb + (size_t)r*DFF;
  float fv[12];
  float s2 = 0.f, z1 = 0.f, z2 = 0.f, z3 = 0.f;
  #pragma unroll
  for (int l = 0; l < 12; ++l) { fv[l] = fr[threadIdx.x + l*256]; s2 += fv[l]*fv[l]; }
  block_reduce_sum4(s2, z1, z2, z3, sbuf);
  float n = sqrtf(fmaxf(s2, 1e-15f));
  float scl = atanhf(fminf(n, 1.f - 1e-5f))/n;
  float rv[12]; float r2 = 0.f;
  #pragma unroll
  for (int l = 0; l < 12; ++l) { rv[l] = fmaxf(scl*fv[l], 0.f); r2 += rv[l]*rv[l]; }
  float w1 = 0.f, w2 = 0.f, w3 = 0.f;
  block_reduce_sum4(r2, w1, w2, w3, sbuf);
  float nr = sqrtf(fmaxf(r2, 1e-15f));
  float sce = tanhf(nr)/nr;
  #pragma unroll
  for (int l = 0; l < 12; ++l) {
    float o = sce*rv[l];
    fr[threadIdx.x + l*256] = o;
    fbr[threadIdx.x + l*256] = f2bf(o);
  }
}

extern "C" void kernel_launch(void* const* d_in, const int* in_sizes, int n_in,
                              void* d_out, int out_size, void* d_ws, size_t ws_size,
                              hipStream_t stream) {
  const float* x    = (const float*)d_in[0];
  const float* wq   = (const float*)d_in[1];
  const float* bq   = (const float*)d_in[2];
  const float* wk   = (const float*)d_in[3];
  const float* bk   = (const float*)d_in[4];
  const float* wv   = (const float*)d_in[5];
  const float* bv   = (const float*)d_in[6];
  const float* wo   = (const float*)d_in[7];
  const float* bo   = (const float*)d_in[8];
  const float* hs   = (const float*)d_in[9];
  const float* w1   = (const float*)d_in[10];
  const float* b1   = (const float*)d_in[11];
  const float* w2   = (const float*)d_in[12];
  const float* b2   = (const float*)d_in[13];
  const float* beta = (const float*)d_in[14];
  const float* ln1w = (const float*)d_in[15];
  const float* ln1b = (const float*)d_in[16];
  const float* ln2w = (const float*)d_in[17];
  const float* ln2b = (const float*)d_in[18];
  float* out = (float*)d_out;

  char* base = (char*)d_ws;
  size_t off = 0;
  auto allocB = [&](size_t bytes) {
    off = (off + 63) & ~(size_t)63;
    void* p = base + off; off += bytes; return p;
  };
  short* bfp  = (short*)allocB((size_t)BF_TOTAL * 2);          // bf16 pool
  short* aob  = (short*)allocB((size_t)NROWS*DMODEL * 2);
  short* hbb  = (short*)allocB((size_t)NROWS*DMODEL * 2);
  short* fbb  = (short*)allocB((size_t)NROWS*DFF * 2);
  float* tq   = (float*)allocB((size_t)NROWS*DMODEL * 4);
  float* tk   = (float*)allocB((size_t)NROWS*DMODEL * 4);  // also: pvraw, aop
  float* tv   = (float*)allocB((size_t)NROWS*DMODEL * 4);  // also: f2
  short* qhb  = (short*)allocB((size_t)NHROWS*DHEAD * 2);
  short* khb  = (short*)allocB((size_t)NHROWS*DHEAD * 2);
  float* q2s  = (float*)allocB((size_t)NHROWS * 4);
  float* k2s  = (float*)allocB((size_t)NHROWS * 4);
  short* lvT  = (short*)allocB((size_t)NBH*DHEAD*P_P * 2);
  float* ao   = (float*)allocB((size_t)NROWS*DMODEL * 4);
  float* hb   = (float*)allocB((size_t)NROWS*DMODEL * 4);
  float* tmpF = (float*)allocB((size_t)NROWS*DFF * 4);
  float* fbuf = (float*)allocB((size_t)NROWS*DFF * 4);

  // aliases (liveness-disjoint in stream order)
  float* sraw  = tmpF;            // 24*196*208 f32 = 3.91 MB <= 4.82 MB
  short* Pbuf  = (short*)fbuf;    // 24*196*256 bf16 = 2.41 MB <= 4.82 MB
  float* pvraw = tk;              // 24*196*64 f32 == NROWS*DMODEL f32 exactly

  const short* xb  = bfp + XB_OFF;
  const short* wqb = bfp + WQ_OFF;
  const short* wkb = bfp + WK_OFF;
  const short* wvb = bfp + WV_OFF;
  const short* wob = bfp + WO_OFF;
  const short* w1b = bfp + W1_OFF;
  const short* w2b = bfp + W2_OFF;

  dim3 blk(256);
  dim3 gCVT(1152, 7);
  dim3 gQKV(DMODEL/64, (NROWS+63)/64, 3);   // 12 x 7 x 3
  dim3 gD(DMODEL/64,  (NROWS+63)/64, 1);    // 12 x 7
  dim3 gF(DFF/64,     (NROWS+63)/64, 1);    // 48 x 7
  dim3 gQK(4, 4, NBH);                      // 384 blocks
  dim3 gPV(1, 4, NBH);                      // 96 blocks

  // convert x + all weights to bf16
  cvt_bf16<<<gCVT, blk, 0, stream>>>(x, wq, wk, wv, wo, w1, w2, bfp);

  // QKV projections + fused post (head-major bf16 Q/K + norms + logmap0(v) transposed)
  gemm_bf16<<<gQKV, blk, 0, stream>>>(xb, wqb, wkb, wvb, tq, tk, tv, NROWS, DMODEL, DMODEL);
  qkv_post<<<dim3(NROWS, 3), blk, 0, stream>>>(x, tq, tk, tv, bq, bk, bv,
                                               qhb, khb, q2s, k2s, lvT);

  // attention: S = QK^T (MFMA), dist+softmax, PV (MFMA), expmap0
  gemm_qk<<<gQK, blk, 0, stream>>>(qhb, khb, sraw);
  soft_dist<<<NHROWS/4, blk, 0, stream>>>(sraw, q2s, k2s, hs, Pbuf);
  gemm_pv<<<gPV, blk, 0, stream>>>(Pbuf, lvT, pvraw);
  expmap_rows<<<NHROWS/4, blk, 0, stream>>>(pvraw, ao, aob);

  // output projection
  gemm_bf16<<<gD, blk, 0, stream>>>(aob, wob, wob, wob, tq, tq, tq, NROWS, DMODEL, DMODEL);
  hyp_linear_post<<<NROWS, blk, 0, stream>>>(ao, tq, bo, tk, DMODEL, DMODEL);

  // residual 1 + hyp layer norm
  resid_ln<<<NROWS, blk, 0, stream>>>(x, tk, beta, ln1w, ln1b, hb, hbb);

  // FFN
  gemm_bf16<<<gF, blk, 0, stream>>>(hbb, w1b, w1b, w1b, tmpF, tmpF, tmpF, NROWS, DMODEL, DFF);
  hyp_linear_post<<<NROWS, blk, 0, stream>>>(hb, tmpF, b1, fbuf, DMODEL, DFF);
  mobius_relu<<<NROWS, blk, 0, stream>>>(fbuf, fbb);
  gemm_bf16<<<gD, blk, 0, stream>>>(fbb, w2b, w2b, w2b, tq, tq, tq, NROWS, DFF, DMODEL);
  hyp_linear_post<<<NROWS, blk, 0, stream>>>(fbuf, tq, b2, tv, DFF, DMODEL);

  // residual 2 + hyp layer norm -> out
  resid_ln<<<NROWS, blk, 0, stream>>>(hb, tv, beta, ln2w, ln2b, out, nullptr);
}

// Round 9
// 129.297 us; speedup vs baseline: 1.3454x; 1.0828x over previous
//
#include <hip/hip_runtime.h>
#include <hip/hip_bf16.h>
#include <math.h>

#define BATCH 2
#define SEQ 196
#define DMODEL 768
#define NHEAD 12
#define DHEAD 64
#define DFF 3072
#define NROWS (BATCH*SEQ)        // 392
#define NBH   (BATCH*NHEAD)     // 24
#define NHROWS (NBH*SEQ)        // 4704

typedef __attribute__((ext_vector_type(8))) short short8;
typedef __attribute__((ext_vector_type(4))) float f32x4;

// bf16 scratch layout (element offsets within the bf16 pool)
#define XB_OFF   0
#define XB_LEN   (NROWS*DMODEL)
#define WQ_OFF   (XB_OFF + XB_LEN)
#define WD_LEN   (DMODEL*DMODEL)
#define WK_OFF   (WQ_OFF + WD_LEN)
#define WV_OFF   (WK_OFF + WD_LEN)
#define WO_OFF   (WV_OFF + WD_LEN)
#define W1_OFF   (WO_OFF + WD_LEN)
#define WF_LEN   (DFF*DMODEL)
#define W2_OFF   (W1_OFF + WF_LEN)
#define BF_TOTAL (W2_OFF + WF_LEN)

// ---------- utilities ----------
__device__ __forceinline__ short f2bf(float f) {
  unsigned u = __builtin_bit_cast(unsigned, f);
  u += 0x7FFFu + ((u >> 16) & 1u);      // round-to-nearest-even
  return (short)(u >> 16);
}
__device__ __forceinline__ float bf2f(short s) {
  unsigned u = ((unsigned)(unsigned short)s) << 16;
  return __builtin_bit_cast(float, u);
}
__device__ __forceinline__ float wave_sum64(float v) {
  #pragma unroll
  for (int off = 32; off; off >>= 1) v += __shfl_xor(v, off);
  return v;
}

__device__ __forceinline__ void block_reduce_sum4(float& a, float& b, float& c, float& d,
                                                  float* sbuf /*>=16 floats*/) {
  #pragma unroll
  for (int off = 32; off; off >>= 1) {
    a += __shfl_xor(a, off);
    b += __shfl_xor(b, off);
    c += __shfl_xor(c, off);
    d += __shfl_xor(d, off);
  }
  int wid = threadIdx.x >> 6;
  if ((threadIdx.x & 63) == 0) {
    sbuf[wid*4+0] = a; sbuf[wid*4+1] = b; sbuf[wid*4+2] = c; sbuf[wid*4+3] = d;
  }
  __syncthreads();
  a = sbuf[0] + sbuf[4] + sbuf[8]  + sbuf[12];
  b = sbuf[1] + sbuf[5] + sbuf[9]  + sbuf[13];
  c = sbuf[2] + sbuf[6] + sbuf[10] + sbuf[14];
  d = sbuf[3] + sbuf[7] + sbuf[11] + sbuf[15];
  __syncthreads();
}

// ---------- convert f32 -> bf16 pool ----------
__global__ __launch_bounds__(256) void cvt_bf16(
    const float* __restrict__ x,  const float* __restrict__ wq,
    const float* __restrict__ wk, const float* __restrict__ wv,
    const float* __restrict__ wo, const float* __restrict__ w1,
    const float* __restrict__ w2, short* __restrict__ d) {
  const float* s; size_t n, o;
  switch (blockIdx.y) {
    case 0: s = x;  n = XB_LEN; o = XB_OFF; break;
    case 1: s = wq; n = WD_LEN; o = WQ_OFF; break;
    case 2: s = wk; n = WD_LEN; o = WK_OFF; break;
    case 3: s = wv; n = WD_LEN; o = WV_OFF; break;
    case 4: s = wo; n = WD_LEN; o = WO_OFF; break;
    case 5: s = w1; n = WF_LEN; o = W1_OFF; break;
    default: s = w2; n = WF_LEN; o = W2_OFF; break;
  }
  size_t units = n >> 3;
  for (size_t u = (size_t)blockIdx.x*256 + threadIdx.x; u < units; u += (size_t)gridDim.x*256) {
    const f32x4* sp = (const f32x4*)(s + u*8);
    f32x4 v0 = sp[0], v1 = sp[1];
    short8 r;
    #pragma unroll
    for (int j = 0; j < 4; ++j) { r[j] = f2bf(v0[j]); r[j+4] = f2bf(v1[j]); }
    *(short8*)(d + o + u*8) = r;
  }
}

// ---------- bf16 MFMA GEMM: Y[n][m] = X[n][K] @ W[m][K]^T ----------
#define PITCH 72
__global__ __launch_bounds__(256) void gemm_bf16(
    const short* __restrict__ X,
    const short* __restrict__ W1p, const short* __restrict__ W2p, const short* __restrict__ W3p,
    float* __restrict__ Y1, float* __restrict__ Y2, float* __restrict__ Y3,
    int n, int K, int m) {
  const short* W = W1p; float* Y = Y1;
  if (blockIdx.z == 1) { W = W2p; Y = Y2; }
  else if (blockIdx.z == 2) { W = W3p; Y = Y3; }

  __shared__ short As[64*PITCH];
  __shared__ short Bs[64*PITCH];
  const int tid  = threadIdx.x;
  const int lane = tid & 63;
  const int w    = tid >> 6, wr = w >> 1, wc = w & 1;
  const int brow = blockIdx.y * 64, bcol = blockIdx.x * 64;

  const int sr = tid >> 2, sc = (tid & 3) * 16;
  const bool rok = (brow + sr) < n;
  const short* xp = X + (size_t)(brow + sr) * K + sc;
  const short* wp = W + (size_t)(bcol + sr) * K + sc;

  f32x4 acc[2][2] = {};
  const int kgo = (lane >> 4) * 8;
  const short8 zero8 = {0,0,0,0,0,0,0,0};

  short8 xa0, xa1, wa0, wa1;
  if (rok) { xa0 = *(const short8*)(xp); xa1 = *(const short8*)(xp + 8); }
  else     { xa0 = zero8; xa1 = zero8; }
  wa0 = *(const short8*)(wp); wa1 = *(const short8*)(wp + 8);

  const int T = K / 64;
  for (int t = 0; t < T; ++t) {
    short8 xn0, xn1, wn0, wn1;
    const int kn = (t + 1 < T) ? (t + 1) * 64 : 0;
    if (rok) { xn0 = *(const short8*)(xp + kn); xn1 = *(const short8*)(xp + kn + 8); }
    else     { xn0 = zero8; xn1 = zero8; }
    wn0 = *(const short8*)(wp + kn); wn1 = *(const short8*)(wp + kn + 8);

    __syncthreads();
    *(short8*)&As[sr*PITCH + sc]     = xa0;
    *(short8*)&As[sr*PITCH + sc + 8] = xa1;
    *(short8*)&Bs[sr*PITCH + sc]     = wa0;
    *(short8*)&Bs[sr*PITCH + sc + 8] = wa1;
    __syncthreads();

    #pragma unroll
    for (int kk = 0; kk < 2; ++kk) {
      short8 a0 = *(const short8*)&As[(wr*32      + (lane & 15))*PITCH + kk*32 + kgo];
      short8 a1 = *(const short8*)&As[(wr*32 + 16 + (lane & 15))*PITCH + kk*32 + kgo];
      short8 b0 = *(const short8*)&Bs[(wc*32      + (lane & 15))*PITCH + kk*32 + kgo];
      short8 b1 = *(const short8*)&Bs[(wc*32 + 16 + (lane & 15))*PITCH + kk*32 + kgo];
      acc[0][0] = __builtin_amdgcn_mfma_f32_16x16x32_bf16(a0, b0, acc[0][0], 0, 0, 0);
      acc[0][1] = __builtin_amdgcn_mfma_f32_16x16x32_bf16(a0, b1, acc[0][1], 0, 0, 0);
      acc[1][0] = __builtin_amdgcn_mfma_f32_16x16x32_bf16(a1, b0, acc[1][0], 0, 0, 0);
      acc[1][1] = __builtin_amdgcn_mfma_f32_16x16x32_bf16(a1, b1, acc[1][1], 0, 0, 0);
    }
    xa0 = xn0; xa1 = xn1; wa0 = wn0; wa1 = wn1;
  }

  const int ccol = bcol + wc*32 + (lane & 15);
  #pragma unroll
  for (int mr = 0; mr < 2; ++mr) {
    #pragma unroll
    for (int j = 0; j < 4; ++j) {
      int grow = brow + wr*32 + mr*16 + (lane >> 4)*4 + j;
      if (grow < n) {
        float* yr = Y + (size_t)grow * m + ccol;
        yr[0]  = acc[mr][0][j];
        yr[16] = acc[mr][1][j];
      }
    }
  }
}

// ---------- fused QKV post (unchanged, round-7-verified) ----------
#define P_P 256
__global__ __launch_bounds__(256) void qkv_post(const float* __restrict__ X,
                                                const float* __restrict__ MQ,
                                                const float* __restrict__ MK,
                                                const float* __restrict__ MV,
                                                const float* __restrict__ bq,
                                                const float* __restrict__ bk,
                                                const float* __restrict__ bv,
                                                short* __restrict__ qhb,
                                                short* __restrict__ khb,
                                                float* __restrict__ q2s,
                                                float* __restrict__ k2s,
                                                short* __restrict__ lvT) {
  __shared__ float sbuf[16];
  const int r = blockIdx.x;
  const int b = r / SEQ, s = r % SEQ;
  const int y = blockIdx.y;
  const float* MX   = (y == 0) ? MQ : (y == 1) ? MK : MV;
  const float* bias = (y == 0) ? bq : (y == 1) ? bk : bv;
  const float* xr = X + (size_t)r*DMODEL;
  const float* mr = MX + (size_t)r*DMODEL;
  const int tid = threadIdx.x, wid = tid >> 6, lane = tid & 63;
  const float maxn = 1.0f - 1e-5f;

  float xs = 0.f, ms = 0.f, mb = 0.f, bb = 0.f;
  float mv[3], bvv[3];
  #pragma unroll
  for (int l = 0; l < 3; ++l) {
    int i = tid + l*256;
    float xv = xr[i];
    mv[l] = mr[i]; bvv[l] = bias[i];
    xs += xv*xv; ms += mv[l]*mv[l]; mb += mv[l]*bvv[l]; bb += bvv[l]*bvv[l];
  }
  block_reduce_sum4(xs, ms, mb, bb, sbuf);
  float xn  = sqrtf(fmaxf(xs, 1e-15f));
  float mxn = sqrtf(fmaxf(ms, 1e-15f));
  float art = atanhf(fminf(xn, maxn));
  float scm = tanhf(mxn/xn*art)/mxn;
  float x2 = scm*scm*ms;
  float y2 = bb;
  float xy = scm*mb;
  float den = fmaxf(1.f + 2.f*xy + x2*y2, 1e-15f);
  float ca = (1.f + 2.f*xy + y2) * scm / den;
  float cb = (1.f - x2) / den;

  #pragma unroll
  for (int l = 0; l < 3; ++l) {
    float o = ca*mv[l] + cb*bvv[l];
    int h = l*4 + wid;
    size_t hr = (size_t)(b*NHEAD + h)*SEQ + s;
    if (y < 2) {
      short c16 = f2bf(fminf(o, maxn));
      float cf = bf2f(c16);
      float nn = wave_sum64(cf*cf);
      if (y == 0) {
        qhb[hr*64 + lane] = c16;
        if (lane == 0) q2s[hr] = nn;
      } else {
        khb[hr*64 + lane] = c16;
        if (lane == 0) k2s[hr] = nn;
      }
    } else {
      float nn = wave_sum64(o*o);
      float n = sqrtf(fmaxf(nn, 1e-15f));
      float scl = atanhf(fminf(n, maxn))/n;
      lvT[((size_t)(b*NHEAD + h)*DHEAD + lane)*P_P + s] = f2bf(scl*o);
    }
  }
}

// ---------- fully fused attention: S=QK^T -> dist+softmax -> PV -> expmap0 ----------
// one block per (b,h, 64-row tile); 4 waves (2x2); ~43KB LDS (P overlays Q/K staging)
#define SP 72      // Q/K staging pitch (bf16 elems)
#define PP 264     // P LDS pitch (bf16 elems, 528B rows, 16B aligned)
__global__ __launch_bounds__(256) void attn_mfma(
    const short* __restrict__ qhb, const short* __restrict__ khb,
    const float* __restrict__ q2s, const float* __restrict__ k2s,
    const short* __restrict__ lvT, const float* __restrict__ hs,
    float* __restrict__ ao, short* __restrict__ aob) {
  __shared__ __align__(16) char smem[9216 + 224*SP*2];   // Qs[64][72] + Ks[224][72]; P[64][264] overlays
  __shared__ float q2l[64];
  __shared__ float k2l[224];
  __shared__ float redA[64][2];
  __shared__ float redB[64][2];

  const int tile = blockIdx.x, bh = blockIdx.z;
  const int h = bh % NHEAD, b = bh / NHEAD;
  const int i0 = tile*64;
  const int tid = threadIdx.x, lane = tid & 63, w = tid >> 6, wr = w >> 1, wc = w & 1;
  short* Qs = (short*)smem;
  short* Ks = (short*)(smem + 9216);
  short* Pl = (short*)smem;
  const short8 z8 = {0,0,0,0,0,0,0,0};
  const int kgo = (lane >> 4)*8;

  // stage Q tile (64 rows x 64) — exactly one pass of 256 threads
  {
    int row = tid >> 2, seg = (tid & 3)*16;
    int gr = i0 + row;
    short8 v0 = z8, v1 = z8;
    if (gr < SEQ) {
      const short* p = qhb + ((size_t)bh*SEQ + gr)*64 + seg;
      v0 = *(const short8*)p; v1 = *(const short8*)(p + 8);
    }
    *(short8*)&Qs[row*SP + seg]     = v0;
    *(short8*)&Qs[row*SP + seg + 8] = v1;
  }
  // stage K (224 rows x 64; rows >=196 zero)
  for (int u = tid; u < 224*4; u += 256) {
    int row = u >> 2, seg = (u & 3)*16;
    short8 v0 = z8, v1 = z8;
    if (row < SEQ) {
      const short* p = khb + ((size_t)bh*SEQ + row)*64 + seg;
      v0 = *(const short8*)p; v1 = *(const short8*)(p + 8);
    }
    *(short8*)&Ks[row*SP + seg]     = v0;
    *(short8*)&Ks[row*SP + seg + 8] = v1;
  }
  if (tid < 64)  q2l[tid] = (i0 + tid < SEQ) ? q2s[(size_t)bh*SEQ + i0 + tid] : 0.f;
  if (tid < 224) k2l[tid] = (tid < SEQ) ? k2s[(size_t)bh*SEQ + tid] : 0.f;
  __syncthreads();

  // S = Q . K^T : per wave rows wr*32..+32, cols wc*112..+112 (7 frags)
  f32x4 acc[2][7] = {};
  #pragma unroll
  for (int kk = 0; kk < 2; ++kk) {
    short8 a0 = *(const short8*)&Qs[(wr*32      + (lane & 15))*SP + kk*32 + kgo];
    short8 a1 = *(const short8*)&Qs[(wr*32 + 16 + (lane & 15))*SP + kk*32 + kgo];
    #pragma unroll
    for (int cf = 0; cf < 7; ++cf) {
      short8 bf = *(const short8*)&Ks[(wc*112 + cf*16 + (lane & 15))*SP + kk*32 + kgo];
      acc[0][cf] = __builtin_amdgcn_mfma_f32_16x16x32_bf16(a0, bf, acc[0][cf], 0, 0, 0);
      acc[1][cf] = __builtin_amdgcn_mfma_f32_16x16x32_bf16(a1, bf, acc[1][cf], 0, 0, 0);
    }
  }

  // dist transform in-register, then row max partials
  const float inv_hsv = 1.f/(hs[h]*8.0f);
  #pragma unroll
  for (int rf = 0; rf < 2; ++rf) {
    #pragma unroll
    for (int j = 0; j < 4; ++j) {
      int rl = wr*32 + rf*16 + (lane >> 4)*4 + j;
      float q2 = q2l[rl];
      #pragma unroll
      for (int cf = 0; cf < 7; ++cf) {
        int col = wc*112 + cf*16 + (lane & 15);
        float kq = acc[rf][cf][j];
        float k2 = k2l[col];
        float xy = -kq;
        float al = 1.f + 2.f*xy + q2;
        float be = 1.f - k2;
        float num2 = al*al*k2 + 2.f*al*be*xy + be*be*q2;
        float den  = fmaxf(1.f + 2.f*xy + k2*q2, 1e-15f);
        float dns  = num2/(den*den);
        float denom = (1.f - q2)*(1.f - k2) + 1e-15f;
        float arg = fmaxf(1.f + 2.f*dns/denom, 1.f + 1e-7f);
        float dist = logf(arg + sqrtf(arg*arg - 1.f));
        acc[rf][cf][j] = (col < SEQ) ? -dist*inv_hsv : -1e30f;
      }
      float m = acc[rf][0][j];
      #pragma unroll
      for (int cf = 1; cf < 7; ++cf) m = fmaxf(m, acc[rf][cf][j]);
      m = fmaxf(m, __shfl_xor(m, 1));
      m = fmaxf(m, __shfl_xor(m, 2));
      m = fmaxf(m, __shfl_xor(m, 4));
      m = fmaxf(m, __shfl_xor(m, 8));
      if ((lane & 15) == 0) redA[rl][wc] = m;
    }
  }
  __syncthreads();   // also: all Qs/Ks reads complete

  // exp + row sum partials
  #pragma unroll
  for (int rf = 0; rf < 2; ++rf) {
    #pragma unroll
    for (int j = 0; j < 4; ++j) {
      int rl = wr*32 + rf*16 + (lane >> 4)*4 + j;
      float m = fmaxf(redA[rl][0], redA[rl][1]);
      float s = 0.f;
      #pragma unroll
      for (int cf = 0; cf < 7; ++cf) {
        float e = expf(acc[rf][cf][j] - m);
        acc[rf][cf][j] = e;
        s += e;
      }
      s += __shfl_xor(s, 1); s += __shfl_xor(s, 2);
      s += __shfl_xor(s, 4); s += __shfl_xor(s, 8);
      if ((lane & 15) == 0) redB[rl][wc] = s;
    }
  }
  __syncthreads();

  // normalize, write P (overlays Qs/Ks)
  #pragma unroll
  for (int rf = 0; rf < 2; ++rf) {
    #pragma unroll
    for (int j = 0; j < 4; ++j) {
      int rl = wr*32 + rf*16 + (lane >> 4)*4 + j;
      float inv = 1.f/(redB[rl][0] + redB[rl][1]);
      #pragma unroll
      for (int cf = 0; cf < 7; ++cf) {
        int col = wc*112 + cf*16 + (lane & 15);
        Pl[rl*PP + col] = f2bf(acc[rf][cf][j]*inv);
      }
    }
  }
  __syncthreads();

  // PV: per wave rows wr*32..+32, cols (head dims) wc*32..+32; K = 224 (cols 196..223 are exact zeros in P)
  f32x4 acc2[2][2] = {};
  const short* lvb = lvT + (size_t)bh*DHEAD*P_P;
  #pragma unroll
  for (int ks = 0; ks < 7; ++ks) {
    short8 a0 = *(const short8*)&Pl[(wr*32      + (lane & 15))*PP + ks*32 + kgo];
    short8 a1 = *(const short8*)&Pl[(wr*32 + 16 + (lane & 15))*PP + ks*32 + kgo];
    short8 b0 = *(const short8*)(lvb + (size_t)(wc*32      + (lane & 15))*P_P + ks*32 + kgo);
    short8 b1 = *(const short8*)(lvb + (size_t)(wc*32 + 16 + (lane & 15))*P_P + ks*32 + kgo);
    acc2[0][0] = __builtin_amdgcn_mfma_f32_16x16x32_bf16(a0, b0, acc2[0][0], 0, 0, 0);
    acc2[0][1] = __builtin_amdgcn_mfma_f32_16x16x32_bf16(a0, b1, acc2[0][1], 0, 0, 0);
    acc2[1][0] = __builtin_amdgcn_mfma_f32_16x16x32_bf16(a1, b0, acc2[1][0], 0, 0, 0);
    acc2[1][1] = __builtin_amdgcn_mfma_f32_16x16x32_bf16(a1, b1, acc2[1][1], 0, 0, 0);
  }

  // expmap0 row-norm partials (redA safe to reuse: last read was before prev barrier)
  #pragma unroll
  for (int rf = 0; rf < 2; ++rf) {
    #pragma unroll
    for (int j = 0; j < 4; ++j) {
      int rl = wr*32 + rf*16 + (lane >> 4)*4 + j;
      float s = acc2[rf][0][j]*acc2[rf][0][j] + acc2[rf][1][j]*acc2[rf][1][j];
      s += __shfl_xor(s, 1); s += __shfl_xor(s, 2);
      s += __shfl_xor(s, 4); s += __shfl_xor(s, 8);
      if ((lane & 15) == 0) redA[rl][wc] = s;
    }
  }
  __syncthreads();

  #pragma unroll
  for (int rf = 0; rf < 2; ++rf) {
    #pragma unroll
    for (int j = 0; j < 4; ++j) {
      int rl = wr*32 + rf*16 + (lane >> 4)*4 + j;
      int grow = i0 + rl;
      if (grow < SEQ) {
        float n2 = redA[rl][0] + redA[rl][1];
        float n = sqrtf(fmaxf(n2, 1e-15f));
        float scl = tanhf(n)/n;
        #pragma unroll
        for (int cf2 = 0; cf2 < 2; ++cf2) {
          int col = h*64 + wc*32 + cf2*16 + (lane & 15);
          float o = scl*acc2[rf][cf2][j];
          size_t idx = (size_t)(b*SEQ + grow)*DMODEL + col;
          ao[idx] = o;
          aob[idx] = f2bf(o);
        }
      }
    }
  }
}

// ---------- fused hyp_linear epilogue + residual + hyp layer norm ----------
// Xfull!=null: xs = ||Xfull row||^2 (din wide); else xs = xsArr[r].
__global__ __launch_bounds__(256) void post_resid_ln(
    const float* __restrict__ Xfull, const float* __restrict__ xsArr, int din,
    const float* __restrict__ MX, const float* __restrict__ bias,
    const float* __restrict__ RX,
    const float* __restrict__ betap, const float* __restrict__ lnw,
    const float* __restrict__ lnb,
    float* __restrict__ out, short* __restrict__ outb) {
  __shared__ float sbuf[16];
  const int r = blockIdx.x;
  const int tid = threadIdx.x;
  const float* mr = MX + (size_t)r*DMODEL;

  float xs = 0.f, ms = 0.f, mb = 0.f, bb = 0.f;
  float mv[3], bvv[3];
  #pragma unroll
  for (int l = 0; l < 3; ++l) {
    int i = tid + l*256;
    mv[l] = mr[i]; bvv[l] = bias[i];
    ms += mv[l]*mv[l]; mb += mv[l]*bvv[l]; bb += bvv[l]*bvv[l];
  }
  if (Xfull) {
    const float* xr = Xfull + (size_t)r*din;
    for (int i = tid; i < din; i += 256) { float v = xr[i]; xs += v*v; }
  }
  block_reduce_sum4(xs, ms, mb, bb, sbuf);
  if (!Xfull) xs = xsArr[r];

  // hyp_linear epilogue
  float xn  = sqrtf(fmaxf(xs, 1e-15f));
  float mxn = sqrtf(fmaxf(ms, 1e-15f));
  float art = atanhf(fminf(xn, 1.f - 1e-5f));
  float scm = tanhf(mxn/xn*art)/mxn;
  float px2 = scm*scm*ms;
  float py2 = bb;
  float pxy = scm*mb;
  float pden = fmaxf(1.f + 2.f*pxy + px2*py2, 1e-15f);
  float pca = (1.f + 2.f*pxy + py2) * scm / pden;
  float pcb = (1.f - px2) / pden;

  // y = pca*mv + pcb*bv; residual with RX
  const float* xr2 = RX + (size_t)r*DMODEL;
  float xv[3], yv[3];
  float x2 = 0.f, xy = 0.f, d1 = 0.f, d2 = 0.f;
  #pragma unroll
  for (int l = 0; l < 3; ++l) {
    int i = tid + l*256;
    xv[l] = xr2[i];
    yv[l] = pca*mv[l] + pcb*bvv[l];
    x2 += xv[l]*xv[l]; xy += xv[l]*yv[l];
  }
  block_reduce_sum4(x2, xy, d1, d2, sbuf);
  float yy = pca*pca*ms + 2.f*pca*pcb*mb + pcb*pcb*bb;

  // mobius_scalar_mul(beta, y) + mobius_add(x, .)
  float beta = betap[0];
  float ny = sqrtf(fmaxf(yy, 1e-15f));
  float scs = tanhf(beta * atanhf(fminf(ny, 1.f - 1e-5f))) / ny;
  float y2  = scs*scs*yy;
  float xys = scs*xy;
  float den = fmaxf(1.f + 2.f*xys + x2*y2, 1e-15f);
  float ca = (1.f + 2.f*xys + y2)/den;
  float cb = (1.f - x2)*scs/den;
  float hv[3]; float h2 = 0.f;
  #pragma unroll
  for (int l = 0; l < 3; ++l) { hv[l] = ca*xv[l] + cb*yv[l]; h2 += hv[l]*hv[l]; }
  float z1 = 0.f, z2 = 0.f, z3 = 0.f;
  block_reduce_sum4(h2, z1, z2, z3, sbuf);

  // logmap0 -> layer norm -> expmap0
  float nh = sqrtf(fmaxf(h2, 1e-15f));
  float scl = atanhf(fminf(nh, 1.f - 1e-5f))/nh;
  float tv[3]; float tsum = 0.f, tsq = 0.f;
  #pragma unroll
  for (int l = 0; l < 3; ++l) { tv[l] = scl*hv[l]; tsum += tv[l]; tsq += tv[l]*tv[l]; }
  float zz = 0.f, zw = 0.f;
  block_reduce_sum4(tsum, tsq, zz, zw, sbuf);
  float mu  = tsum * (1.f/768.f);
  float var = tsq * (1.f/768.f) - mu*mu;
  float rstd = rsqrtf(var + 1e-5f);
  float lnv[3]; float l2 = 0.f;
  #pragma unroll
  for (int l = 0; l < 3; ++l) {
    int i = tid + l*256;
    lnv[l] = (tv[l] - mu)*rstd*lnw[i] + lnb[i];
    l2 += lnv[l]*lnv[l];
  }
  float w1 = 0.f, w2 = 0.f, w3 = 0.f;
  block_reduce_sum4(l2, w1, w2, w3, sbuf);
  float nl = sqrtf(fmaxf(l2, 1e-15f));
  float sce = tanhf(nl)/nl;
  #pragma unroll
  for (int l = 0; l < 3; ++l) {
    int i = tid + l*256;
    float o = sce*lnv[l];
    out[(size_t)r*DMODEL + i] = o;
    if (outb) outb[(size_t)r*DMODEL + i] = f2bf(o);
  }
}

// ---------- fused FFN1 epilogue: hyp_linear post + mobius_relu -> bf16 + row norm ----------
__global__ __launch_bounds__(256) void ffn1_post(const float* __restrict__ hb,
                                                 const float* __restrict__ MX,
                                                 const float* __restrict__ bias,
                                                 short* __restrict__ fbb,
                                                 float* __restrict__ fnorm) {
  __shared__ float sbuf[16];
  const int r = blockIdx.x;
  const int tid = threadIdx.x;
  const float* xr = hb + (size_t)r*DMODEL;
  const float* mr = MX + (size_t)r*DFF;

  float xs = 0.f, ms = 0.f, mb = 0.f, bb = 0.f;
  float mv[12], bvv[12];
  for (int i = tid; i < DMODEL; i += 256) { float v = xr[i]; xs += v*v; }
  #pragma unroll
  for (int l = 0; l < 12; ++l) {
    int i = tid + l*256;
    mv[l] = mr[i]; bvv[l] = bias[i];
    ms += mv[l]*mv[l]; mb += mv[l]*bvv[l]; bb += bvv[l]*bvv[l];
  }
  block_reduce_sum4(xs, ms, mb, bb, sbuf);
  float xn  = sqrtf(fmaxf(xs, 1e-15f));
  float mxn = sqrtf(fmaxf(ms, 1e-15f));
  float art = atanhf(fminf(xn, 1.f - 1e-5f));
  float scm = tanhf(mxn/xn*art)/mxn;
  float px2 = scm*scm*ms;
  float py2 = bb;
  float pxy = scm*mb;
  float pden = fmaxf(1.f + 2.f*pxy + px2*py2, 1e-15f);
  float pca = (1.f + 2.f*pxy + py2) * scm / pden;
  float pcb = (1.f - px2) / pden;

  // f = pca*mv + pcb*bv ; ||f||^2 analytically
  float s2 = pca*pca*ms + 2.f*pca*pcb*mb + pcb*pcb*bb;
  float n = sqrtf(fmaxf(s2, 1e-15f));
  float scl = atanhf(fminf(n, 1.f - 1e-5f))/n;
  float rv[12]; float r2 = 0.f;
  #pragma unroll
  for (int l = 0; l < 12; ++l) {
    float f = pca*mv[l] + pcb*bvv[l];
    rv[l] = fmaxf(scl*f, 0.f);
    r2 += rv[l]*rv[l];
  }
  float w1 = 0.f, w2 = 0.f, w3 = 0.f;
  block_reduce_sum4(r2, w1, w2, w3, sbuf);
  float nr = sqrtf(fmaxf(r2, 1e-15f));
  float sce = tanhf(nr)/nr;
  #pragma unroll
  for (int l = 0; l < 12; ++l)
    fbb[(size_t)r*DFF + tid + l*256] = f2bf(sce*rv[l]);
  if (tid == 0) fnorm[r] = sce*sce*r2;   // ||output row||^2
}

extern "C" void kernel_launch(void* const* d_in, const int* in_sizes, int n_in,
                              void* d_out, int out_size, void* d_ws, size_t ws_size,
                              hipStream_t stream) {
  const float* x    = (const float*)d_in[0];
  const float* wq   = (const float*)d_in[1];
  const float* bq   = (const float*)d_in[2];
  const float* wk   = (const float*)d_in[3];
  const float* bk   = (const float*)d_in[4];
  const float* wv   = (const float*)d_in[5];
  const float* bv   = (const float*)d_in[6];
  const float* wo   = (const float*)d_in[7];
  const float* bo   = (const float*)d_in[8];
  const float* hs   = (const float*)d_in[9];
  const float* w1   = (const float*)d_in[10];
  const float* b1   = (const float*)d_in[11];
  const float* w2   = (const float*)d_in[12];
  const float* b2   = (const float*)d_in[13];
  const float* beta = (const float*)d_in[14];
  const float* ln1w = (const float*)d_in[15];
  const float* ln1b = (const float*)d_in[16];
  const float* ln2w = (const float*)d_in[17];
  const float* ln2b = (const float*)d_in[18];
  float* out = (float*)d_out;

  char* base = (char*)d_ws;
  size_t off = 0;
  auto allocB = [&](size_t bytes) {
    off = (off + 63) & ~(size_t)63;
    void* p = base + off; off += bytes; return p;
  };
  short* bfp  = (short*)allocB((size_t)BF_TOTAL * 2);
  short* aob  = (short*)allocB((size_t)NROWS*DMODEL * 2);
  short* hbb  = (short*)allocB((size_t)NROWS*DMODEL * 2);
  short* fbb  = (short*)allocB((size_t)NROWS*DFF * 2);
  float* tq   = (float*)allocB((size_t)NROWS*DMODEL * 4);
  float* tk   = (float*)allocB((size_t)NROWS*DMODEL * 4);
  float* tv   = (float*)allocB((size_t)NROWS*DMODEL * 4);
  short* qhb  = (short*)allocB((size_t)NHROWS*DHEAD * 2);
  short* khb  = (short*)allocB((size_t)NHROWS*DHEAD * 2);
  float* q2s  = (float*)allocB((size_t)NHROWS * 4);
  float* k2s  = (float*)allocB((size_t)NHROWS * 4);
  short* lvT  = (short*)allocB((size_t)NBH*DHEAD*P_P * 2);
  float* ao   = (float*)allocB((size_t)NROWS*DMODEL * 4);
  float* hb   = (float*)allocB((size_t)NROWS*DMODEL * 4);
  float* tmpF = (float*)allocB((size_t)NROWS*DFF * 4);
  float* fnorm= (float*)allocB((size_t)NROWS * 4);

  const short* xb  = bfp + XB_OFF;
  const short* wqb = bfp + WQ_OFF;
  const short* wkb = bfp + WK_OFF;
  const short* wvb = bfp + WV_OFF;
  const short* wob = bfp + WO_OFF;
  const short* w1b = bfp + W1_OFF;
  const short* w2b = bfp + W2_OFF;

  dim3 blk(256);
  dim3 gCVT(1152, 7);
  dim3 gQKV(DMODEL/64, (NROWS+63)/64, 3);
  dim3 gD(DMODEL/64,  (NROWS+63)/64, 1);
  dim3 gF(DFF/64,     (NROWS+63)/64, 1);
  dim3 gATT(4, 1, NBH);                     // 96 blocks

  // convert x + all weights to bf16
  cvt_bf16<<<gCVT, blk, 0, stream>>>(x, wq, wk, wv, wo, w1, w2, bfp);

  // QKV projections + fused post
  gemm_bf16<<<gQKV, blk, 0, stream>>>(xb, wqb, wkb, wvb, tq, tk, tv, NROWS, DMODEL, DMODEL);
  qkv_post<<<dim3(NROWS, 3), blk, 0, stream>>>(x, tq, tk, tv, bq, bk, bv,
                                               qhb, khb, q2s, k2s, lvT);

  // fused attention
  attn_mfma<<<gATT, blk, 0, stream>>>(qhb, khb, q2s, k2s, lvT, hs, ao, aob);

  // output projection + fused post/residual/LN1
  gemm_bf16<<<gD, blk, 0, stream>>>(aob, wob, wob, wob, tq, tq, tq, NROWS, DMODEL, DMODEL);
  post_resid_ln<<<NROWS, blk, 0, stream>>>(ao, nullptr, DMODEL, tq, bo, x,
                                           beta, ln1w, ln1b, hb, hbb);

  // FFN
  gemm_bf16<<<gF, blk, 0, stream>>>(hbb, w1b, w1b, w1b, tmpF, tmpF, tmpF, NROWS, DMODEL, DFF);
  ffn1_post<<<NROWS, blk, 0, stream>>>(hb, tmpF, b1, fbb, fnorm);
  gemm_bf16<<<gD, blk, 0, stream>>>(fbb, w2b, w2b, w2b, tq, tq, tq, NROWS, DFF, DMODEL);
  post_resid_ln<<<NROWS, blk, 0, stream>>>(nullptr, fnorm, DFF, tq, b2, hb,
                                           beta, ln2w, ln2b, out, nullptr);
}

// Round 12
// 111.629 us; speedup vs baseline: 1.5584x; 1.1583x over previous
//
#include <hip/hip_runtime.h>
#include <hip/hip_bf16.h>
#include <math.h>

#define BATCH 2
#define SEQ 196
#define DMODEL 768
#define NHEAD 12
#define DHEAD 64
#define DFF 3072
#define NROWS (BATCH*SEQ)        // 392
#define NBH   (BATCH*NHEAD)     // 24
#define NHROWS (NBH*SEQ)        // 4704

typedef __attribute__((ext_vector_type(8))) short short8;
typedef __attribute__((ext_vector_type(4))) float f32x4;

// ---------- utilities ----------
__device__ __forceinline__ short f2bf(float f) {
  unsigned u = __builtin_bit_cast(unsigned, f);
  u += 0x7FFFu + ((u >> 16) & 1u);      // round-to-nearest-even
  return (short)(u >> 16);
}
__device__ __forceinline__ float bf2f(short s) {
  unsigned u = ((unsigned)(unsigned short)s) << 16;
  return __builtin_bit_cast(float, u);
}
__device__ __forceinline__ float wave_sum64(float v) {
  #pragma unroll
  for (int off = 32; off; off >>= 1) v += __shfl_xor(v, off);
  return v;
}

__device__ __forceinline__ void block_reduce_sum4(float& a, float& b, float& c, float& d,
                                                  float* sbuf /*>=16 floats*/) {
  #pragma unroll
  for (int off = 32; off; off >>= 1) {
    a += __shfl_xor(a, off);
    b += __shfl_xor(b, off);
    c += __shfl_xor(c, off);
    d += __shfl_xor(d, off);
  }
  int wid = threadIdx.x >> 6;
  if ((threadIdx.x & 63) == 0) {
    sbuf[wid*4+0] = a; sbuf[wid*4+1] = b; sbuf[wid*4+2] = c; sbuf[wid*4+3] = d;
  }
  __syncthreads();
  a = sbuf[0] + sbuf[4] + sbuf[8]  + sbuf[12];
  b = sbuf[1] + sbuf[5] + sbuf[9]  + sbuf[13];
  c = sbuf[2] + sbuf[6] + sbuf[10] + sbuf[14];
  d = sbuf[3] + sbuf[7] + sbuf[11] + sbuf[15];
  __syncthreads();
}

#define PITCH 72

// ---------- QKV GEMM: f32 inputs, inline bf16 conversion; z selects wq/wk/wv ----------
__global__ __launch_bounds__(256) void gemm_qkv_f32(
    const float* __restrict__ X,
    const float* __restrict__ Wq, const float* __restrict__ Wk, const float* __restrict__ Wv,
    float* __restrict__ Yq, float* __restrict__ Yk, float* __restrict__ Yv) {
  const float* W = Wq; float* Y = Yq;
  if (blockIdx.z == 1) { W = Wk; Y = Yk; }
  else if (blockIdx.z == 2) { W = Wv; Y = Yv; }
  const int K = DMODEL, m = DMODEL, n = NROWS;

  __shared__ short As[64*PITCH];
  __shared__ short Bs[64*PITCH];
  const int tid  = threadIdx.x;
  const int lane = tid & 63;
  const int w    = tid >> 6, wr = w >> 1, wc = w & 1;
  const int brow = blockIdx.y * 64, bcol = blockIdx.x * 64;

  const int sr = tid >> 2, sc = (tid & 3) * 16;
  const bool rok = (brow + sr) < n;
  const float* xp = X + (size_t)(brow + sr) * K + sc;
  const float* wp = W + (size_t)(bcol + sr) * K + sc;

  f32x4 acc[2][2] = {};
  const int kgo = (lane >> 4) * 8;
  const f32x4 zf = {0.f,0.f,0.f,0.f};

  f32x4 xa[4], wa[4];
  #pragma unroll
  for (int q = 0; q < 4; ++q) {
    xa[q] = rok ? *(const f32x4*)(xp + q*4) : zf;
    wa[q] = *(const f32x4*)(wp + q*4);
  }

  const int T = K / 64;
  for (int t = 0; t < T; ++t) {
    f32x4 xn[4], wn[4];
    const int kn = (t + 1 < T) ? (t + 1) * 64 : 0;
    #pragma unroll
    for (int q = 0; q < 4; ++q) {
      xn[q] = rok ? *(const f32x4*)(xp + kn + q*4) : zf;
      wn[q] = *(const f32x4*)(wp + kn + q*4);
    }

    short8 xs0, xs1, ws0, ws1;
    #pragma unroll
    for (int j = 0; j < 4; ++j) {
      xs0[j] = f2bf(xa[0][j]); xs0[j+4] = f2bf(xa[1][j]);
      xs1[j] = f2bf(xa[2][j]); xs1[j+4] = f2bf(xa[3][j]);
      ws0[j] = f2bf(wa[0][j]); ws0[j+4] = f2bf(wa[1][j]);
      ws1[j] = f2bf(wa[2][j]); ws1[j+4] = f2bf(wa[3][j]);
    }
    __syncthreads();
    *(short8*)&As[sr*PITCH + sc]     = xs0;
    *(short8*)&As[sr*PITCH + sc + 8] = xs1;
    *(short8*)&Bs[sr*PITCH + sc]     = ws0;
    *(short8*)&Bs[sr*PITCH + sc + 8] = ws1;
    __syncthreads();

    #pragma unroll
    for (int kk = 0; kk < 2; ++kk) {
      short8 a0 = *(const short8*)&As[(wr*32      + (lane & 15))*PITCH + kk*32 + kgo];
      short8 a1 = *(const short8*)&As[(wr*32 + 16 + (lane & 15))*PITCH + kk*32 + kgo];
      short8 b0 = *(const short8*)&Bs[(wc*32      + (lane & 15))*PITCH + kk*32 + kgo];
      short8 b1 = *(const short8*)&Bs[(wc*32 + 16 + (lane & 15))*PITCH + kk*32 + kgo];
      acc[0][0] = __builtin_amdgcn_mfma_f32_16x16x32_bf16(a0, b0, acc[0][0], 0, 0, 0);
      acc[0][1] = __builtin_amdgcn_mfma_f32_16x16x32_bf16(a0, b1, acc[0][1], 0, 0, 0);
      acc[1][0] = __builtin_amdgcn_mfma_f32_16x16x32_bf16(a1, b0, acc[1][0], 0, 0, 0);
      acc[1][1] = __builtin_amdgcn_mfma_f32_16x16x32_bf16(a1, b1, acc[1][1], 0, 0, 0);
    }
    #pragma unroll
    for (int q = 0; q < 4; ++q) { xa[q] = xn[q]; wa[q] = wn[q]; }
  }

  const int ccol = bcol + wc*32 + (lane & 15);
  #pragma unroll
  for (int mr = 0; mr < 2; ++mr) {
    #pragma unroll
    for (int j = 0; j < 4; ++j) {
      int grow = brow + wr*32 + mr*16 + (lane >> 4)*4 + j;
      if (grow < n) {
        float* yr = Y + (size_t)grow * m + ccol;
        yr[0]  = acc[mr][0][j];
        yr[16] = acc[mr][1][j];
      }
    }
  }
}

// ---------- GEMM: A bf16, W f32 (inline cvt), split-K via blockIdx.z ----------
// Yparts[z][n][m]; z covers K-range [z*KK, (z+1)*KK)
__global__ __launch_bounds__(256) void gemm_awf32(
    const short* __restrict__ A, const float* __restrict__ W,
    float* __restrict__ Yparts, int n, int Ktot, int m, int KK) {
  const int z = blockIdx.z;
  const int kbase = z * KK;
  float* Y = Yparts + (size_t)z * n * m;

  __shared__ short As[64*PITCH];
  __shared__ short Bs[64*PITCH];
  const int tid  = threadIdx.x;
  const int lane = tid & 63;
  const int w    = tid >> 6, wr = w >> 1, wc = w & 1;
  const int brow = blockIdx.y * 64, bcol = blockIdx.x * 64;

  const int sr = tid >> 2, sc = (tid & 3) * 16;
  const bool rok = (brow + sr) < n;
  const short* ap = A + (size_t)(brow + sr) * Ktot + kbase + sc;
  const float* wp = W + (size_t)(bcol + sr) * Ktot + kbase + sc;

  f32x4 acc[2][2] = {};
  const int kgo = (lane >> 4) * 8;
  const short8 z8 = {0,0,0,0,0,0,0,0};
  const f32x4 zf = {0.f,0.f,0.f,0.f};

  short8 aa0, aa1;
  f32x4 wa[4];
  if (rok) { aa0 = *(const short8*)(ap); aa1 = *(const short8*)(ap + 8); }
  else     { aa0 = z8; aa1 = z8; }
  #pragma unroll
  for (int q = 0; q < 4; ++q) wa[q] = *(const f32x4*)(wp + q*4);

  const int T = KK / 64;
  for (int t = 0; t < T; ++t) {
    short8 an0, an1;
    f32x4 wn[4];
    const int kn = (t + 1 < T) ? (t + 1) * 64 : 0;
    if (rok) { an0 = *(const short8*)(ap + kn); an1 = *(const short8*)(ap + kn + 8); }
    else     { an0 = z8; an1 = z8; }
    #pragma unroll
    for (int q = 0; q < 4; ++q) wn[q] = *(const f32x4*)(wp + kn + q*4);

    short8 ws0, ws1;
    #pragma unroll
    for (int j = 0; j < 4; ++j) {
      ws0[j] = f2bf(wa[0][j]); ws0[j+4] = f2bf(wa[1][j]);
      ws1[j] = f2bf(wa[2][j]); ws1[j+4] = f2bf(wa[3][j]);
    }
    __syncthreads();
    *(short8*)&As[sr*PITCH + sc]     = aa0;
    *(short8*)&As[sr*PITCH + sc + 8] = aa1;
    *(short8*)&Bs[sr*PITCH + sc]     = ws0;
    *(short8*)&Bs[sr*PITCH + sc + 8] = ws1;
    __syncthreads();

    #pragma unroll
    for (int kk = 0; kk < 2; ++kk) {
      short8 a0 = *(const short8*)&As[(wr*32      + (lane & 15))*PITCH + kk*32 + kgo];
      short8 a1 = *(const short8*)&As[(wr*32 + 16 + (lane & 15))*PITCH + kk*32 + kgo];
      short8 b0 = *(const short8*)&Bs[(wc*32      + (lane & 15))*PITCH + kk*32 + kgo];
      short8 b1 = *(const short8*)&Bs[(wc*32 + 16 + (lane & 15))*PITCH + kk*32 + kgo];
      acc[0][0] = __builtin_amdgcn_mfma_f32_16x16x32_bf16(a0, b0, acc[0][0], 0, 0, 0);
      acc[0][1] = __builtin_amdgcn_mfma_f32_16x16x32_bf16(a0, b1, acc[0][1], 0, 0, 0);
      acc[1][0] = __builtin_amdgcn_mfma_f32_16x16x32_bf16(a1, b0, acc[1][0], 0, 0, 0);
      acc[1][1] = __builtin_amdgcn_mfma_f32_16x16x32_bf16(a1, b1, acc[1][1], 0, 0, 0);
    }
    aa0 = an0; aa1 = an1;
    #pragma unroll
    for (int q = 0; q < 4; ++q) wa[q] = wn[q];
  }

  const int ccol = bcol + wc*32 + (lane & 15);
  #pragma unroll
  for (int mr = 0; mr < 2; ++mr) {
    #pragma unroll
    for (int j = 0; j < 4; ++j) {
      int grow = brow + wr*32 + mr*16 + (lane >> 4)*4 + j;
      if (grow < n) {
        float* yr = Y + (size_t)grow * m + ccol;
        yr[0]  = acc[mr][0][j];
        yr[16] = acc[mr][1][j];
      }
    }
  }
}

// ---------- fused QKV post (round-7-verified) ----------
#define P_P 256
__global__ __launch_bounds__(256) void qkv_post(const float* __restrict__ X,
                                                const float* __restrict__ MQ,
                                                const float* __restrict__ MK,
                                                const float* __restrict__ MV,
                                                const float* __restrict__ bq,
                                                const float* __restrict__ bk,
                                                const float* __restrict__ bv,
                                                short* __restrict__ qhb,
                                                short* __restrict__ khb,
                                                float* __restrict__ q2s,
                                                float* __restrict__ k2s,
                                                short* __restrict__ lvT) {
  __shared__ float sbuf[16];
  const int r = blockIdx.x;
  const int b = r / SEQ, s = r % SEQ;
  const int y = blockIdx.y;
  const float* MX   = (y == 0) ? MQ : (y == 1) ? MK : MV;
  const float* bias = (y == 0) ? bq : (y == 1) ? bk : bv;
  const float* xr = X + (size_t)r*DMODEL;
  const float* mr = MX + (size_t)r*DMODEL;
  const int tid = threadIdx.x, wid = tid >> 6, lane = tid & 63;
  const float maxn = 1.0f - 1e-5f;

  float xs = 0.f, ms = 0.f, mb = 0.f, bb = 0.f;
  float mv[3], bvv[3];
  #pragma unroll
  for (int l = 0; l < 3; ++l) {
    int i = tid + l*256;
    float xv = xr[i];
    mv[l] = mr[i]; bvv[l] = bias[i];
    xs += xv*xv; ms += mv[l]*mv[l]; mb += mv[l]*bvv[l]; bb += bvv[l]*bvv[l];
  }
  block_reduce_sum4(xs, ms, mb, bb, sbuf);
  float xn  = sqrtf(fmaxf(xs, 1e-15f));
  float mxn = sqrtf(fmaxf(ms, 1e-15f));
  float art = atanhf(fminf(xn, maxn));
  float scm = tanhf(mxn/xn*art)/mxn;
  float x2 = scm*scm*ms;
  float y2 = bb;
  float xy = scm*mb;
  float den = fmaxf(1.f + 2.f*xy + x2*y2, 1e-15f);
  float ca = (1.f + 2.f*xy + y2) * scm / den;
  float cb = (1.f - x2) / den;

  #pragma unroll
  for (int l = 0; l < 3; ++l) {
    float o = ca*mv[l] + cb*bvv[l];
    int h = l*4 + wid;
    size_t hr = (size_t)(b*NHEAD + h)*SEQ + s;
    if (y < 2) {
      short c16 = f2bf(fminf(o, maxn));
      float cf = bf2f(c16);
      float nn = wave_sum64(cf*cf);
      if (y == 0) {
        qhb[hr*64 + lane] = c16;
        if (lane == 0) q2s[hr] = nn;
      } else {
        khb[hr*64 + lane] = c16;
        if (lane == 0) k2s[hr] = nn;
      }
    } else {
      float nn = wave_sum64(o*o);
      float n = sqrtf(fmaxf(nn, 1e-15f));
      float scl = atanhf(fminf(n, maxn))/n;
      lvT[((size_t)(b*NHEAD + h)*DHEAD + lane)*P_P + s] = f2bf(scl*o);
    }
  }
}

// ---------- fully fused attention: S=QK^T -> dist+softmax -> PV -> expmap0 ----------
#define SP 72
#define PP 264
__global__ __launch_bounds__(256) void attn_mfma(
    const short* __restrict__ qhb, const short* __restrict__ khb,
    const float* __restrict__ q2s, const float* __restrict__ k2s,
    const short* __restrict__ lvT, const float* __restrict__ hs,
    short* __restrict__ aob) {
  __shared__ __align__(16) char smem[9216 + 224*SP*2];
  __shared__ float q2l[64];
  __shared__ float k2l[224];
  __shared__ float redA[64][2];
  __shared__ float redB[64][2];

  const int tile = blockIdx.x, bh = blockIdx.z;
  const int h = bh % NHEAD, b = bh / NHEAD;
  const int i0 = tile*64;
  const int tid = threadIdx.x, lane = tid & 63, w = tid >> 6, wr = w >> 1, wc = w & 1;
  short* Qs = (short*)smem;
  short* Ks = (short*)(smem + 9216);
  short* Pl = (short*)smem;
  const short8 z8 = {0,0,0,0,0,0,0,0};
  const int kgo = (lane >> 4)*8;

  {
    int row = tid >> 2, seg = (tid & 3)*16;
    int gr = i0 + row;
    short8 v0 = z8, v1 = z8;
    if (gr < SEQ) {
      const short* p = qhb + ((size_t)bh*SEQ + gr)*64 + seg;
      v0 = *(const short8*)p; v1 = *(const short8*)(p + 8);
    }
    *(short8*)&Qs[row*SP + seg]     = v0;
    *(short8*)&Qs[row*SP + seg + 8] = v1;
  }
  for (int u = tid; u < 224*4; u += 256) {
    int row = u >> 2, seg = (u & 3)*16;
    short8 v0 = z8, v1 = z8;
    if (row < SEQ) {
      const short* p = khb + ((size_t)bh*SEQ + row)*64 + seg;
      v0 = *(const short8*)p; v1 = *(const short8*)(p + 8);
    }
    *(short8*)&Ks[row*SP + seg]     = v0;
    *(short8*)&Ks[row*SP + seg + 8] = v1;
  }
  if (tid < 64)  q2l[tid] = (i0 + tid < SEQ) ? q2s[(size_t)bh*SEQ + i0 + tid] : 0.f;
  if (tid < 224) k2l[tid] = (tid < SEQ) ? k2s[(size_t)bh*SEQ + tid] : 0.f;
  __syncthreads();

  f32x4 acc[2][7] = {};
  #pragma unroll
  for (int kk = 0; kk < 2; ++kk) {
    short8 a0 = *(const short8*)&Qs[(wr*32      + (lane & 15))*SP + kk*32 + kgo];
    short8 a1 = *(const short8*)&Qs[(wr*32 + 16 + (lane & 15))*SP + kk*32 + kgo];
    #pragma unroll
    for (int cf = 0; cf < 7; ++cf) {
      short8 bf = *(const short8*)&Ks[(wc*112 + cf*16 + (lane & 15))*SP + kk*32 + kgo];
      acc[0][cf] = __builtin_amdgcn_mfma_f32_16x16x32_bf16(a0, bf, acc[0][cf], 0, 0, 0);
      acc[1][cf] = __builtin_amdgcn_mfma_f32_16x16x32_bf16(a1, bf, acc[1][cf], 0, 0, 0);
    }
  }

  const float inv_hsv = 1.f/(hs[h]*8.0f);
  #pragma unroll
  for (int rf = 0; rf < 2; ++rf) {
    #pragma unroll
    for (int j = 0; j < 4; ++j) {
      int rl = wr*32 + rf*16 + (lane >> 4)*4 + j;
      float q2 = q2l[rl];
      #pragma unroll
      for (int cf = 0; cf < 7; ++cf) {
        int col = wc*112 + cf*16 + (lane & 15);
        float kq = acc[rf][cf][j];
        float k2 = k2l[col];
        float xy = -kq;
        float al = 1.f + 2.f*xy + q2;
        float be = 1.f - k2;
        float num2 = al*al*k2 + 2.f*al*be*xy + be*be*q2;
        float den  = fmaxf(1.f + 2.f*xy + k2*q2, 1e-15f);
        float dns  = num2/(den*den);
        float denom = (1.f - q2)*(1.f - k2) + 1e-15f;
        float arg = fmaxf(1.f + 2.f*dns/denom, 1.f + 1e-7f);
        float dist = logf(arg + sqrtf(arg*arg - 1.f));
        acc[rf][cf][j] = (col < SEQ) ? -dist*inv_hsv : -1e30f;
      }
      float m = acc[rf][0][j];
      #pragma unroll
      for (int cf = 1; cf < 7; ++cf) m = fmaxf(m, acc[rf][cf][j]);
      m = fmaxf(m, __shfl_xor(m, 1));
      m = fmaxf(m, __shfl_xor(m, 2));
      m = fmaxf(m, __shfl_xor(m, 4));
      m = fmaxf(m, __shfl_xor(m, 8));
      if ((lane & 15) == 0) redA[rl][wc] = m;
    }
  }
  __syncthreads();

  #pragma unroll
  for (int rf = 0; rf < 2; ++rf) {
    #pragma unroll
    for (int j = 0; j < 4; ++j) {
      int rl = wr*32 + rf*16 + (lane >> 4)*4 + j;
      float m = fmaxf(redA[rl][0], redA[rl][1]);
      float s = 0.f;
      #pragma unroll
      for (int cf = 0; cf < 7; ++cf) {
        float e = expf(acc[rf][cf][j] - m);
        acc[rf][cf][j] = e;
        s += e;
      }
      s += __shfl_xor(s, 1); s += __shfl_xor(s, 2);
      s += __shfl_xor(s, 4); s += __shfl_xor(s, 8);
      if ((lane & 15) == 0) redB[rl][wc] = s;
    }
  }
  __syncthreads();

  #pragma unroll
  for (int rf = 0; rf < 2; ++rf) {
    #pragma unroll
    for (int j = 0; j < 4; ++j) {
      int rl = wr*32 + rf*16 + (lane >> 4)*4 + j;
      float inv = 1.f/(redB[rl][0] + redB[rl][1]);
      #pragma unroll
      for (int cf = 0; cf < 7; ++cf) {
        int col = wc*112 + cf*16 + (lane & 15);
        Pl[rl*PP + col] = f2bf(acc[rf][cf][j]*inv);
      }
    }
  }
  __syncthreads();

  f32x4 acc2[2][2] = {};
  const short* lvb = lvT + (size_t)bh*DHEAD*P_P;
  #pragma unroll
  for (int ks = 0; ks < 7; ++ks) {
    short8 a0 = *(const short8*)&Pl[(wr*32      + (lane & 15))*PP + ks*32 + kgo];
    short8 a1 = *(const short8*)&Pl[(wr*32 + 16 + (lane & 15))*PP + ks*32 + kgo];
    short8 b0 = *(const short8*)(lvb + (size_t)(wc*32      + (lane & 15))*P_P + ks*32 + kgo);
    short8 b1 = *(const short8*)(lvb + (size_t)(wc*32 + 16 + (lane & 15))*P_P + ks*32 + kgo);
    acc2[0][0] = __builtin_amdgcn_mfma_f32_16x16x32_bf16(a0, b0, acc2[0][0], 0, 0, 0);
    acc2[0][1] = __builtin_amdgcn_mfma_f32_16x16x32_bf16(a0, b1, acc2[0][1], 0, 0, 0);
    acc2[1][0] = __builtin_amdgcn_mfma_f32_16x16x32_bf16(a1, b0, acc2[1][0], 0, 0, 0);
    acc2[1][1] = __builtin_amdgcn_mfma_f32_16x16x32_bf16(a1, b1, acc2[1][1], 0, 0, 0);
  }

  #pragma unroll
  for (int rf = 0; rf < 2; ++rf) {
    #pragma unroll
    for (int j = 0; j < 4; ++j) {
      int rl = wr*32 + rf*16 + (lane >> 4)*4 + j;
      float s = acc2[rf][0][j]*acc2[rf][0][j] + acc2[rf][1][j]*acc2[rf][1][j];
      s += __shfl_xor(s, 1); s += __shfl_xor(s, 2);
      s += __shfl_xor(s, 4); s += __shfl_xor(s, 8);
      if ((lane & 15) == 0) redA[rl][wc] = s;
    }
  }
  __syncthreads();

  #pragma unroll
  for (int rf = 0; rf < 2; ++rf) {
    #pragma unroll
    for (int j = 0; j < 4; ++j) {
      int rl = wr*32 + rf*16 + (lane >> 4)*4 + j;
      int grow = i0 + rl;
      if (grow < SEQ) {
        float n2 = redA[rl][0] + redA[rl][1];
        float n = sqrtf(fmaxf(n2, 1e-15f));
        float scl = tanhf(n)/n;
        #pragma unroll
        for (int cf2 = 0; cf2 < 2; ++cf2) {
          int col = h*64 + wc*32 + cf2*16 + (lane & 15);
          float o = scl*acc2[rf][cf2][j];
          aob[(size_t)(b*SEQ + grow)*DMODEL + col] = f2bf(o);
        }
      }
    }
  }
}

// ---------- fused hyp_linear epilogue + residual + hyp layer norm (split-K partial sum) ----------
// Xbf!=null: xs = ||bf16 Xbf row||^2 (din wide); else xs = xsArr[r].
__global__ __launch_bounds__(256) void post_resid_ln(
    const short* __restrict__ Xbf, const float* __restrict__ xsArr, int din,
    const float* __restrict__ MXp, int nparts,
    const float* __restrict__ bias, const float* __restrict__ RX,
    const float* __restrict__ betap, const float* __restrict__ lnw,
    const float* __restrict__ lnb,
    float* __restrict__ out, short* __restrict__ outb) {
  __shared__ float sbuf[16];
  const int r = blockIdx.x;
  const int tid = threadIdx.x;

  float xs = 0.f, ms = 0.f, mb = 0.f, bb = 0.f;
  float mv[3], bvv[3];
  #pragma unroll
  for (int l = 0; l < 3; ++l) {
    int i = tid + l*256;
    float acc = 0.f;
    for (int p = 0; p < nparts; ++p)
      acc += MXp[(size_t)p*NROWS*DMODEL + (size_t)r*DMODEL + i];
    mv[l] = acc; bvv[l] = bias[i];
    ms += mv[l]*mv[l]; mb += mv[l]*bvv[l]; bb += bvv[l]*bvv[l];
  }
  if (Xbf) {
    const short* xr = Xbf + (size_t)r*din;
    for (int i = tid; i < din; i += 256) { float v = bf2f(xr[i]); xs += v*v; }
  }
  block_reduce_sum4(xs, ms, mb, bb, sbuf);
  if (!Xbf) xs = xsArr[r];

  float xn  = sqrtf(fmaxf(xs, 1e-15f));
  float mxn = sqrtf(fmaxf(ms, 1e-15f));
  float art = atanhf(fminf(xn, 1.f - 1e-5f));
  float scm = tanhf(mxn/xn*art)/mxn;
  float px2 = scm*scm*ms;
  float py2 = bb;
  float pxy = scm*mb;
  float pden = fmaxf(1.f + 2.f*pxy + px2*py2, 1e-15f);
  float pca = (1.f + 2.f*pxy + py2) * scm / pden;
  float pcb = (1.f - px2) / pden;

  const float* xr2 = RX + (size_t)r*DMODEL;
  float xv[3], yv[3];
  float x2 = 0.f, xy = 0.f, d1 = 0.f, d2 = 0.f;
  #pragma unroll
  for (int l = 0; l < 3; ++l) {
    int i = tid + l*256;
    xv[l] = xr2[i];
    yv[l] = pca*mv[l] + pcb*bvv[l];
    x2 += xv[l]*xv[l]; xy += xv[l]*yv[l];
  }
  block_reduce_sum4(x2, xy, d1, d2, sbuf);
  float yy = pca*pca*ms + 2.f*pca*pcb*mb + pcb*pcb*bb;

  float beta = betap[0];
  float ny = sqrtf(fmaxf(yy, 1e-15f));
  float scs = tanhf(beta * atanhf(fminf(ny, 1.f - 1e-5f))) / ny;
  float y2  = scs*scs*yy;
  float xys = scs*xy;
  float den = fmaxf(1.f + 2.f*xys + x2*y2, 1e-15f);
  float ca = (1.f + 2.f*xys + y2)/den;
  float cb = (1.f - x2)*scs/den;
  float hv[3]; float h2 = 0.f;
  #pragma unroll
  for (int l = 0; l < 3; ++l) { hv[l] = ca*xv[l] + cb*yv[l]; h2 += hv[l]*hv[l]; }
  float z1 = 0.f, z2 = 0.f, z3 = 0.f;
  block_reduce_sum4(h2, z1, z2, z3, sbuf);

  float nh = sqrtf(fmaxf(h2, 1e-15f));
  float scl = atanhf(fminf(nh, 1.f - 1e-5f))/nh;
  float tv[3]; float tsum = 0.f, tsq = 0.f;
  #pragma unroll
  for (int l = 0; l < 3; ++l) { tv[l] = scl*hv[l]; tsum += tv[l]; tsq += tv[l]*tv[l]; }
  float zz = 0.f, zw = 0.f;
  block_reduce_sum4(tsum, tsq, zz, zw, sbuf);
  float mu  = tsum * (1.f/768.f);
  float var = tsq * (1.f/768.f) - mu*mu;
  float rstd = rsqrtf(var + 1e-5f);
  float lnv[3]; float l2 = 0.f;
  #pragma unroll
  for (int l = 0; l < 3; ++l) {
    int i = tid + l*256;
    lnv[l] = (tv[l] - mu)*rstd*lnw[i] + lnb[i];
    l2 += lnv[l]*lnv[l];
  }
  float w1 = 0.f, w2 = 0.f, w3 = 0.f;
  block_reduce_sum4(l2, w1, w2, w3, sbuf);
  float nl = sqrtf(fmaxf(l2, 1e-15f));
  float sce = tanhf(nl)/nl;
  #pragma unroll
  for (int l = 0; l < 3; ++l) {
    int i = tid + l*256;
    float o = sce*lnv[l];
    out[(size_t)r*DMODEL + i] = o;
    if (outb) outb[(size_t)r*DMODEL + i] = f2bf(o);
  }
}

// ---------- fused FFN1 epilogue: hyp_linear post + mobius_relu -> bf16 + row norm ----------
__global__ __launch_bounds__(256) void ffn1_post(const float* __restrict__ hb,
                                                 const float* __restrict__ MX,
                                                 const float* __restrict__ bias,
                                                 short* __restrict__ fbb,
                                                 float* __restrict__ fnorm) {
  __shared__ float sbuf[16];
  const int r = blockIdx.x;
  const int tid = threadIdx.x;
  const float* xr = hb + (size_t)r*DMODEL;
  const float* mr = MX + (size_t)r*DFF;

  float xs = 0.f, ms = 0.f, mb = 0.f, bb = 0.f;
  float mv[12], bvv[12];
  for (int i = tid; i < DMODEL; i += 256) { float v = xr[i]; xs += v*v; }
  #pragma unroll
  for (int l = 0; l < 12; ++l) {
    int i = tid + l*256;
    mv[l] = mr[i]; bvv[l] = bias[i];
    ms += mv[l]*mv[l]; mb += mv[l]*bvv[l]; bb += bvv[l]*bvv[l];
  }
  block_reduce_sum4(xs, ms, mb, bb, sbuf);
  float xn  = sqrtf(fmaxf(xs, 1e-15f));
  float mxn = sqrtf(fmaxf(ms, 1e-15f));
  float art = atanhf(fminf(xn, 1.f - 1e-5f));
  float scm = tanhf(mxn/xn*art)/mxn;
  float px2 = scm*scm*ms;
  float py2 = bb;
  float pxy = scm*mb;
  float pden = fmaxf(1.f + 2.f*pxy + px2*py2, 1e-15f);
  float pca = (1.f + 2.f*pxy + py2) * scm / pden;
  float pcb = (1.f - px2) / pden;

  float s2 = pca*pca*ms + 2.f*pca*pcb*mb + pcb*pcb*bb;
  float n = sqrtf(fmaxf(s2, 1e-15f));
  float scl = atanhf(fminf(n, 1.f - 1e-5f))/n;
  float rv[12]; float r2 = 0.f;
  #pragma unroll
  for (int l = 0; l < 12; ++l) {
    float f = pca*mv[l] + pcb*bvv[l];
    rv[l] = fmaxf(scl*f, 0.f);
    r2 += rv[l]*rv[l];
  }
  float w1 = 0.f, w2 = 0.f, w3 = 0.f;
  block_reduce_sum4(r2, w1, w2, w3, sbuf);
  float nr = sqrtf(fmaxf(r2, 1e-15f));
  float sce = tanhf(nr)/nr;
  #pragma unroll
  for (int l = 0; l < 12; ++l)
    fbb[(size_t)r*DFF + tid + l*256] = f2bf(sce*rv[l]);
  if (tid == 0) fnorm[r] = sce*sce*r2;
}

extern "C" void kernel_launch(void* const* d_in, const int* in_sizes, int n_in,
                              void* d_out, int out_size, void* d_ws, size_t ws_size,
                              hipStream_t stream) {
  const float* x    = (const float*)d_in[0];
  const float* wq   = (const float*)d_in[1];
  const float* bq   = (const float*)d_in[2];
  const float* wk   = (const float*)d_in[3];
  const float* bk   = (const float*)d_in[4];
  const float* wv   = (const float*)d_in[5];
  const float* bv   = (const float*)d_in[6];
  const float* wo   = (const float*)d_in[7];
  const float* bo   = (const float*)d_in[8];
  const float* hs   = (const float*)d_in[9];
  const float* w1   = (const float*)d_in[10];
  const float* b1   = (const float*)d_in[11];
  const float* w2   = (const float*)d_in[12];
  const float* b2   = (const float*)d_in[13];
  const float* beta = (const float*)d_in[14];
  const float* ln1w = (const float*)d_in[15];
  const float* ln1b = (const float*)d_in[16];
  const float* ln2w = (const float*)d_in[17];
  const float* ln2b = (const float*)d_in[18];
  float* out = (float*)d_out;

  char* base = (char*)d_ws;
  size_t off = 0;
  auto allocB = [&](size_t bytes) {
    off = (off + 63) & ~(size_t)63;
    void* p = base + off; off += bytes; return p;
  };
  short* aob  = (short*)allocB((size_t)NROWS*DMODEL * 2);
  short* hbb  = (short*)allocB((size_t)NROWS*DMODEL * 2);
  short* fbb  = (short*)allocB((size_t)NROWS*DFF * 2);
  float* tq   = (float*)allocB((size_t)NROWS*DMODEL * 4);
  float* tk   = (float*)allocB((size_t)NROWS*DMODEL * 4);
  float* tv   = (float*)allocB((size_t)NROWS*DMODEL * 4);
  float* gparts = (float*)allocB((size_t)4*NROWS*DMODEL * 4);   // split-K partials
  short* qhb  = (short*)allocB((size_t)NHROWS*DHEAD * 2);
  short* khb  = (short*)allocB((size_t)NHROWS*DHEAD * 2);
  float* q2s  = (float*)allocB((size_t)NHROWS * 4);
  float* k2s  = (float*)allocB((size_t)NHROWS * 4);
  short* lvT  = (short*)allocB((size_t)NBH*DHEAD*P_P * 2);
  float* hb   = (float*)allocB((size_t)NROWS*DMODEL * 4);
  float* tmpF = (float*)allocB((size_t)NROWS*DFF * 4);
  float* fnorm= (float*)allocB((size_t)NROWS * 4);

  dim3 blk(256);
  dim3 gQKV(DMODEL/64, (NROWS+63)/64, 3);   // 252 blocks
  dim3 gO(DMODEL/64,   (NROWS+63)/64, 2);   // split-K=2, 168 blocks
  dim3 gF1(DFF/64,     (NROWS+63)/64, 1);   // 336 blocks
  dim3 gF2(DMODEL/64,  (NROWS+63)/64, 4);   // split-K=4, 336 blocks
  dim3 gATT(4, 1, NBH);                     // 96 blocks

  // QKV projections (inline f32->bf16) + fused post
  gemm_qkv_f32<<<gQKV, blk, 0, stream>>>(x, wq, wk, wv, tq, tk, tv);
  qkv_post<<<dim3(NROWS, 3), blk, 0, stream>>>(x, tq, tk, tv, bq, bk, bv,
                                               qhb, khb, q2s, k2s, lvT);

  // fused attention
  attn_mfma<<<gATT, blk, 0, stream>>>(qhb, khb, q2s, k2s, lvT, hs, aob);

  // output projection (split-K=2) + fused post/residual/LN1
  gemm_awf32<<<gO, blk, 0, stream>>>(aob, wo, gparts, NROWS, DMODEL, DMODEL, DMODEL/2);
  post_resid_ln<<<NROWS, blk, 0, stream>>>(aob, nullptr, DMODEL, gparts, 2, bo, x,
                                           beta, ln1w, ln1b, hb, hbb);

  // FFN
  gemm_awf32<<<gF1, blk, 0, stream>>>(hbb, w1, tmpF, NROWS, DMODEL, DFF, DMODEL);
  ffn1_post<<<NROWS, blk, 0, stream>>>(hb, tmpF, b1, fbb, fnorm);
  gemm_awf32<<<gF2, blk, 0, stream>>>(fbb, w2, gparts, NROWS, DFF, DMODEL, DFF/4);
  post_resid_ln<<<NROWS, blk, 0, stream>>>(nullptr, fnorm, DFF, gparts, 4, b2, hb,
                                           beta, ln2w, ln2b, out, nullptr);
}